// Round 3
// baseline (17860.519 us; speedup 1.0000x reference)
//
#include <hip/hip_runtime.h>
#include <hip/hip_bf16.h>
#include <stdint.h>

// ---------------------------------------------------------------------------
// CNNLSTM: conv1(6->64,k2) BN ReLU -> conv2(64->64,k2) BN ReLU ->
//          convT1(64->64,k2) BN ReLU -> convT2(64->64,k2) ReLU ->
//          LSTM(T=512, batch=1024, H=64) -> linear(64->1)
// Device I/O: FP32 (reference dtypes). Internal: conv fp32; LSTM MFMA bf16
// with fp32 accum/cell; outputs fp32.
// ws layout: 513 slots of 1024*64 bf16 (slot s = ws + s*65536 elems).
//   conv writes x_t to slot t+1 ; LSTM reads slot t+1, writes h_t to slot t ;
//   projection reads h_t at slot t.  ws bytes needed: 513*65536*2 = 67,239,936.
// ---------------------------------------------------------------------------

typedef __attribute__((ext_vector_type(8))) short bf16x8;
typedef __attribute__((ext_vector_type(4))) float f32x4;

__device__ __forceinline__ float bf2f(uint16_t u) {
  union { uint32_t i; float f; } v; v.i = ((uint32_t)u) << 16; return v.f;
}
__device__ __forceinline__ uint16_t f2bf(float f) {
  union { float f; uint32_t i; } v; v.f = f;
  return (uint16_t)((v.i + 0x7FFFu + ((v.i >> 16) & 1u)) >> 16);  // RNE
}
__device__ __forceinline__ float fexp(float x) { return __builtin_amdgcn_exp2f(x * 1.44269504088896340736f); }
__device__ __forceinline__ float frcp(float x) { return __builtin_amdgcn_rcpf(x); }
__device__ __forceinline__ float fsig(float x)  { return frcp(1.f + fexp(-x)); }
__device__ __forceinline__ float ftanh(float x) { return 1.f - 2.f * frcp(1.f + fexp(2.f * x)); }

// ============================ conv stack ===================================
// Grid: (16 chunks of 64 cols, 512 t). Block 256 thr: lane=h (0..63), 4 waves
// split columns. LDS intermediates fp32, row stride 68.
// Column index il maps to global l: gl = l0 - 2 + il.
__global__ __launch_bounds__(256) void conv_stack_k(
    const float* __restrict__ inp,
    const float* __restrict__ w1p, const float* __restrict__ b1p,
    const float* __restrict__ g1p, const float* __restrict__ be1p,
    const float* __restrict__ m1p, const float* __restrict__ v1p,
    const float* __restrict__ w2p, const float* __restrict__ b2p,
    const float* __restrict__ g2p, const float* __restrict__ be2p,
    const float* __restrict__ m2p, const float* __restrict__ v2p,
    const float* __restrict__ t1p, const float* __restrict__ tb1p,
    const float* __restrict__ g3p, const float* __restrict__ be3p,
    const float* __restrict__ m3p, const float* __restrict__ v3p,
    const float* __restrict__ t2p, const float* __restrict__ tb2p,
    uint16_t* __restrict__ X)
{
  __shared__ float xs[6][68];
  __shared__ float yA[65][68];   // y1, later y3 (+1 guard row, stays 0)
  __shared__ float yB[65][68];   // y2 (+1 guard row, stays 0)
  const int tid = threadIdx.x;
  const int h   = tid & 63;
  const int wv  = tid >> 6;
  const int t   = blockIdx.y;
  const int l0  = blockIdx.x * 64;

  // zero-init yA/yB so any boundary read is 0.0, never garbage/NaN
  for (int i = tid; i < 65 * 68; i += 256) { yA[0][i] = 0.f; yB[0][i] = 0.f; }

  // stage input window: x[t][c][gl], gl in [l0-2, l0+66)
  for (int i = tid; i < 6 * 68; i += 256) {
    int c = i % 6, il = i / 6;
    int gl = l0 - 2 + il;
    float v = 0.f;
    if (gl >= 0 && gl < 1024) v = inp[(size_t)t * 6144 + (size_t)gl * 6 + c];
    xs[c][il] = v;
  }

  // ---- phase 1: y1 = relu(bn1(conv1(x))), valid gl in [0,1023), cols il<67
  {
    float wr[12];
#pragma unroll
    for (int i = 0; i < 6; ++i) {
      float2 q = *(const float2*)(w1p + h * 12 + i * 2);
      wr[i * 2] = q.x; wr[i * 2 + 1] = q.y;
    }
    float sc = g1p[h] * __builtin_amdgcn_rsqf(v1p[h] + 1e-5f);
    float tc = (b1p[h] - m1p[h]) * sc + be1p[h];
    __syncthreads();   // covers zero-init + xs staging
    for (int base = wv * 4; base < 67; base += 16) {
      float a0 = 0, a1 = 0, a2 = 0, a3 = 0;
#pragma unroll
      for (int c = 0; c < 6; ++c) {
        float4 v = *(const float4*)&xs[c][base];
        float s4 = xs[c][base + 4];          // may read past row: masked below
        float k0 = wr[c * 2], k1 = wr[c * 2 + 1];
        a0 += v.x * k0 + v.y * k1;
        a1 += v.y * k0 + v.z * k1;
        a2 += v.z * k0 + v.w * k1;
        a3 += v.w * k0 + s4 * k1;
      }
      float r[4] = {a0, a1, a2, a3};
#pragma unroll
      for (int j = 0; j < 4; ++j) {
        int il = base + j;
        if (il < 67) {
          int gl = l0 - 2 + il;
          yA[h][il] = (gl >= 0 && gl < 1023) ? fmaxf(r[j] * sc + tc, 0.f) : 0.f;
        }
      }
    }
  }
  __syncthreads();

  // ---- phase 2: y2 = relu(bn2(conv2(y1))), valid gl in [0,1022), cols il<66
  {
    float wr[128];
    const float4* wp = (const float4*)(w2p + (size_t)h * 128);
#pragma unroll
    for (int i = 0; i < 32; ++i) {
      float4 q = wp[i];
      wr[i*4+0]=q.x; wr[i*4+1]=q.y; wr[i*4+2]=q.z; wr[i*4+3]=q.w;
    }
    float sc = g2p[h] * __builtin_amdgcn_rsqf(v2p[h] + 1e-5f);
    float tc = (b2p[h] - m2p[h]) * sc + be2p[h];
    for (int base = wv * 8; base < 66; base += 32) {
      float a[8] = {0, 0, 0, 0, 0, 0, 0, 0};
#pragma unroll
      for (int c = 0; c < 64; ++c) {
        float4 v0 = *(const float4*)&yA[c][base];
        float4 v1 = *(const float4*)&yA[c][base + 4];
        float s8  = yA[c][base + 8];
        float k0 = wr[c * 2], k1 = wr[c * 2 + 1];
        a[0] += v0.x * k0 + v0.y * k1;
        a[1] += v0.y * k0 + v0.z * k1;
        a[2] += v0.z * k0 + v0.w * k1;
        a[3] += v0.w * k0 + v1.x * k1;
        a[4] += v1.x * k0 + v1.y * k1;
        a[5] += v1.y * k0 + v1.z * k1;
        a[6] += v1.z * k0 + v1.w * k1;
        a[7] += v1.w * k0 + s8   * k1;
      }
#pragma unroll
      for (int j = 0; j < 8; ++j) {
        int il = base + j;
        if (il < 66) {
          int gl = l0 - 2 + il;
          yB[h][il] = (gl >= 0 && gl < 1022) ? fmaxf(a[j] * sc + tc, 0.f) : 0.f;
        }
      }
    }
  }
  __syncthreads();

  // ---- phase 3: y3 = relu(bn3(convT1(y2))) : y3[l]=y2[l]*w0+y2[l-1]*w1
  //      valid gl in [0,1023), cols 1<=il<66 ; overwrites yA
  {
    float wr[128];
#pragma unroll
    for (int c = 0; c < 64; ++c) {
      float2 q = *(const float2*)(t1p + c * 128 + h * 2);
      wr[c * 2] = q.x; wr[c * 2 + 1] = q.y;
    }
    float sc = g3p[h] * __builtin_amdgcn_rsqf(v3p[h] + 1e-5f);
    float tc = (tb1p[h] - m3p[h]) * sc + be3p[h];
    for (int base = wv * 8; base < 66; base += 32) {
      float a[8] = {0, 0, 0, 0, 0, 0, 0, 0};
#pragma unroll
      for (int c = 0; c < 64; ++c) {
        float4 v0 = *(const float4*)&yB[c][base];
        float4 v1 = *(const float4*)&yB[c][base + 4];
        float sm  = (base > 0) ? yB[c][base - 1] : 0.f;
        float k0 = wr[c * 2], k1 = wr[c * 2 + 1];
        a[0] += v0.x * k0 + sm   * k1;
        a[1] += v0.y * k0 + v0.x * k1;
        a[2] += v0.z * k0 + v0.y * k1;
        a[3] += v0.w * k0 + v0.z * k1;
        a[4] += v1.x * k0 + v0.w * k1;
        a[5] += v1.y * k0 + v1.x * k1;
        a[6] += v1.z * k0 + v1.y * k1;
        a[7] += v1.w * k0 + v1.z * k1;
      }
#pragma unroll
      for (int j = 0; j < 8; ++j) {
        int il = base + j;
        if (il >= 1 && il < 66) {
          int gl = l0 - 2 + il;
          yA[h][il] = (gl >= 0 && gl < 1023) ? fmaxf(a[j] * sc + tc, 0.f) : 0.f;
        }
      }
    }
  }
  __syncthreads();

  // ---- phase 4: y4 = relu(convT2(y3)+b) ; cols 2<=il<66 -> gl in [l0,l0+64)
  //      store transposed (bf16) to X slot t+1 : X[(t+1)][gl][h]
  {
    float wr[128];
#pragma unroll
    for (int c = 0; c < 64; ++c) {
      float2 q = *(const float2*)(t2p + c * 128 + h * 2);
      wr[c * 2] = q.x; wr[c * 2 + 1] = q.y;
    }
    float tb = tb2p[h];
    for (int base = wv * 8; base < 66; base += 32) {
      float a[8] = {0, 0, 0, 0, 0, 0, 0, 0};
#pragma unroll
      for (int c = 0; c < 64; ++c) {
        float4 v0 = *(const float4*)&yA[c][base];
        float4 v1 = *(const float4*)&yA[c][base + 4];
        float sm  = (base > 0) ? yA[c][base - 1] : 0.f;
        float k0 = wr[c * 2], k1 = wr[c * 2 + 1];
        a[0] += v0.x * k0 + sm   * k1;
        a[1] += v0.y * k0 + v0.x * k1;
        a[2] += v0.z * k0 + v0.y * k1;
        a[3] += v0.w * k0 + v0.z * k1;
        a[4] += v1.x * k0 + v0.w * k1;
        a[5] += v1.y * k0 + v1.x * k1;
        a[6] += v1.z * k0 + v1.y * k1;
        a[7] += v1.w * k0 + v1.z * k1;
      }
#pragma unroll
      for (int j = 0; j < 8; ++j) {
        int il = base + j;
        if (il >= 2 && il < 66) {
          int gl = l0 - 2 + il;
          X[(size_t)(t + 1) * 65536 + (size_t)gl * 64 + h] = f2bf(fmaxf(a[j] + tb, 0.f));
        }
      }
    }
  }
}

// ============================== LSTM =======================================
// 64 blocks x 16 batch rows; 4 waves; wave w owns gate cols {16w,+64,+128,+192}
// so each lane holds i,f,g,o of its cells. K=128 = [x_t | h] via 4 MFMA chunks.
// h exchanged through double-buffered LDS (row stride 72 -> only 2-way bank
// aliasing, free). One __syncthreads per step.
#define HSTR 72
#define MFMA16(a, b, c) __builtin_amdgcn_mfma_f32_16x16x32_bf16(a, b, c, 0, 0, 0)

#define LSTM_STEP(T_, XC, XN, BR, BW) do {                                     \
    if ((T_) + 1 < 512) {                                                      \
      const uint16_t* xp_ = Xb + (size_t)((T_) + 2) * 65536                    \
                          + (size_t)(l0 + (lane & 15)) * 64 + kgrp;            \
      XN[0] = *(const bf16x8*)xp_;                                             \
      XN[1] = *(const bf16x8*)(xp_ + 32);                                      \
    }                                                                          \
    bf16x8 hf0_ = *(const bf16x8*)&hl[BR][(lane & 15) * HSTR + kgrp];          \
    bf16x8 hf1_ = *(const bf16x8*)&hl[BR][(lane & 15) * HSTR + 32 + kgrp];     \
    f32x4 ai_ = Z4, af_ = Z4, ag_ = Z4, ao_ = Z4;                              \
    ai_ = MFMA16(XC[0], bfr[0][0], ai_); af_ = MFMA16(XC[0], bfr[1][0], af_);  \
    ag_ = MFMA16(XC[0], bfr[2][0], ag_); ao_ = MFMA16(XC[0], bfr[3][0], ao_);  \
    ai_ = MFMA16(XC[1], bfr[0][1], ai_); af_ = MFMA16(XC[1], bfr[1][1], af_);  \
    ag_ = MFMA16(XC[1], bfr[2][1], ag_); ao_ = MFMA16(XC[1], bfr[3][1], ao_);  \
    ai_ = MFMA16(hf0_,  bfr[0][2], ai_); af_ = MFMA16(hf0_,  bfr[1][2], af_);  \
    ag_ = MFMA16(hf0_,  bfr[2][2], ag_); ao_ = MFMA16(hf0_,  bfr[3][2], ao_);  \
    ai_ = MFMA16(hf1_,  bfr[0][3], ai_); af_ = MFMA16(hf1_,  bfr[1][3], af_);  \
    ag_ = MFMA16(hf1_,  bfr[2][3], ag_); ao_ = MFMA16(hf1_,  bfr[3][3], ao_);  \
    _Pragma("unroll")                                                          \
    for (int r_ = 0; r_ < 4; ++r_) {                                           \
      float ii = fsig(ai_[r_] + bi0);                                          \
      float ff = fsig(af_[r_] + bi1);                                          \
      float gg = ftanh(ag_[r_] + bi2);                                         \
      float oo = fsig(ao_[r_] + bi3);                                          \
      creg[r_] = ff * creg[r_] + ii * gg;                                      \
      hprev[r_] = oo * ftanh(creg[r_]);                                        \
      uint16_t hb_ = f2bf(hprev[r_]);                                          \
      hl[BW][(r0 + r_) * HSTR + hcol] = hb_;                                   \
      Xb[(size_t)(T_) * 65536 + (size_t)(l0 + r0 + r_) * 64 + hcol] = hb_;     \
    }                                                                          \
    __syncthreads();                                                           \
  } while (0)

__global__ __launch_bounds__(256) void lstm_k(
    const float* __restrict__ h0p, const float* __restrict__ c0p,
    const float* __restrict__ wihp, const float* __restrict__ whhp,
    const float* __restrict__ bihp, const float* __restrict__ bhhp,
    uint16_t* __restrict__ Xb, float* __restrict__ outp)
{
  __shared__ __align__(16) uint16_t hl[2][16 * HSTR];
  const int tid  = threadIdx.x;
  const int lane = tid & 63;
  const int wv   = tid >> 6;
  const int l0   = blockIdx.x << 4;
  const int hcol = (wv << 4) | (lane & 15);
  const int r0   = (lane >> 4) << 2;
  const int kgrp = (lane >> 4) << 3;

  // B fragments (loop-invariant, registers): B[k][n], k<64: w_ih, else w_hh
  // fp32 weights converted once to bf16.
  bf16x8 bfr[4][4];
#pragma unroll
  for (int nt = 0; nt < 4; ++nt) {
    int n = nt * 64 + hcol;
#pragma unroll
    for (int kc = 0; kc < 4; ++kc) {
      int k0 = kc * 32 + kgrp;
      const float* src = (k0 < 64) ? (wihp + (size_t)n * 64 + k0)
                                   : (whhp + (size_t)n * 64 + (k0 - 64));
      bf16x8 f;
#pragma unroll
      for (int j = 0; j < 8; ++j) f[j] = (short)f2bf(src[j]);
      bfr[nt][kc] = f;
    }
  }
  float bi0 = bihp[hcol]       + bhhp[hcol];
  float bi1 = bihp[64 + hcol]  + bhhp[64 + hcol];
  float bi2 = bihp[128 + hcol] + bhhp[128 + hcol];
  float bi3 = bihp[192 + hcol] + bhhp[192 + hcol];

  float creg[4], hprev[4] = {0.f, 0.f, 0.f, 0.f};
#pragma unroll
  for (int r = 0; r < 4; ++r)
    creg[r] = c0p[(size_t)(l0 + r0 + r) * 64 + hcol];

  // init h LDS buf 0 from hidden_state (fp32 -> bf16)
  {
    int row = tid >> 4, col = (tid & 15) << 2;
    const float* sp = h0p + (size_t)(l0 + row) * 64 + col;
    int b = row * HSTR + col;
    hl[0][b]     = f2bf(sp[0]); hl[0][b + 1] = f2bf(sp[1]);
    hl[0][b + 2] = f2bf(sp[2]); hl[0][b + 3] = f2bf(sp[3]);
  }

  bf16x8 xA[2], xB[2];
  {
    const uint16_t* xp = Xb + 65536 + (size_t)(l0 + (lane & 15)) * 64 + kgrp;
    xA[0] = *(const bf16x8*)xp;
    xA[1] = *(const bf16x8*)(xp + 32);
  }
  __syncthreads();

  const f32x4 Z4 = {0.f, 0.f, 0.f, 0.f};
#pragma unroll 1
  for (int t2 = 0; t2 < 512; t2 += 2) {
    LSTM_STEP(t2,     xA, xB, 0, 1);
    LSTM_STEP(t2 + 1, xB, xA, 1, 0);
  }

  // hT at out+524288, cT at out+589824 (fp32)
#pragma unroll
  for (int r = 0; r < 4; ++r) {
    int gr = l0 + r0 + r;
    outp[524288 + (size_t)gr * 64 + hcol] = hprev[r];
    outp[589824 + (size_t)gr * 64 + hcol] = creg[r];
  }
}

// ========================= output projection ===============================
__global__ __launch_bounds__(256) void proj_k(
    const uint16_t* __restrict__ Hb, const float* __restrict__ owp,
    const float* __restrict__ obp, float* __restrict__ outp)
{
  __shared__ float ows[64];
  if (threadIdx.x < 64) ows[threadIdx.x] = owp[threadIdx.x];
  __syncthreads();
  int idx = blockIdx.x * 256 + threadIdx.x;     // = t*1024 + l
  const uint16_t* hp = Hb + (size_t)idx * 64;   // slot t, row l
  float s = obp[0];
#pragma unroll
  for (int j = 0; j < 8; ++j) {
    bf16x8 hv = *(const bf16x8*)(hp + j * 8);
#pragma unroll
    for (int e = 0; e < 8; ++e) s += bf2f((uint16_t)hv[e]) * ows[j * 8 + e];
  }
  outp[idx] = s;
}

// ============================== launch =====================================
extern "C" void kernel_launch(void* const* d_in, const int* in_sizes, int n_in,
                              void* d_out, int out_size, void* d_ws, size_t ws_size,
                              hipStream_t stream)
{
  (void)in_sizes; (void)n_in; (void)out_size;
  // ws sanity guard: if too small, leave d_out zeroed (recognizable signature)
  if (ws_size < (size_t)513 * 65536 * 2) return;

  const float* inp = (const float*)d_in[0];
  const float* h0p = (const float*)d_in[1];
  const float* c0p = (const float*)d_in[2];
  const float* w1  = (const float*)d_in[3];
  const float* b1  = (const float*)d_in[4];
  const float* g1  = (const float*)d_in[5];
  const float* be1 = (const float*)d_in[6];
  const float* m1  = (const float*)d_in[7];
  const float* v1  = (const float*)d_in[8];
  const float* w2  = (const float*)d_in[9];
  const float* b2  = (const float*)d_in[10];
  const float* g2  = (const float*)d_in[11];
  const float* be2 = (const float*)d_in[12];
  const float* m2  = (const float*)d_in[13];
  const float* v2  = (const float*)d_in[14];
  const float* tw1 = (const float*)d_in[15];
  const float* tb1 = (const float*)d_in[16];
  const float* g3  = (const float*)d_in[17];
  const float* be3 = (const float*)d_in[18];
  const float* m3  = (const float*)d_in[19];
  const float* v3  = (const float*)d_in[20];
  const float* tw2 = (const float*)d_in[21];
  const float* tb2 = (const float*)d_in[22];
  const float* wih = (const float*)d_in[23];
  const float* whh = (const float*)d_in[24];
  const float* bih = (const float*)d_in[25];
  const float* bhh = (const float*)d_in[26];
  const float* ow  = (const float*)d_in[27];
  const float* ob  = (const float*)d_in[28];

  uint16_t* Xb   = (uint16_t*)d_ws;      // 513 slots of 65536 bf16
  float*    outp = (float*)d_out;

  conv_stack_k<<<dim3(16, 512), 256, 0, stream>>>(
      inp, w1, b1, g1, be1, m1, v1, w2, b2, g2, be2, m2, v2,
      tw1, tb1, g3, be3, m3, v3, tw2, tb2, Xb);
  lstm_k<<<64, 256, 0, stream>>>(h0p, c0p, wih, whh, bih, bhh, Xb, outp);
  proj_k<<<2048, 256, 0, stream>>>(Xb, ow, ob, outp);
}

// Round 4
// 12327.738 us; speedup vs baseline: 1.4488x; 1.4488x over previous
//
#include <hip/hip_runtime.h>
#include <hip/hip_bf16.h>
#include <stdint.h>

// ---------------------------------------------------------------------------
// CNNLSTM: conv1(6->64,k2) BN ReLU -> conv2(64->64,k2) BN ReLU ->
//          convT1(64->64,k2) BN ReLU -> convT2(64->64,k2) ReLU ->
//          LSTM(T=512, batch=1024, H=64) -> linear(64->1)
// Device I/O: FP32. Internal: conv fp32 (weights staged in LDS — round-3
// version spilled 128-float weight arrays to scratch: 23.9 GB HBM traffic);
// LSTM MFMA bf16 with fp32 accum/cell; outputs fp32.
// ws layout: 513 slots of 1024*64 bf16 (slot s = ws + s*65536 elems).
//   conv writes x_t to slot t+1 ; LSTM reads slot t+1, writes h_t to slot t ;
//   projection reads h_t at slot t.  ws bytes needed: 513*65536*2 = 67,239,936.
// ---------------------------------------------------------------------------

typedef __attribute__((ext_vector_type(8))) short bf16x8;
typedef __attribute__((ext_vector_type(4))) float f32x4;

__device__ __forceinline__ float bf2f(uint16_t u) {
  union { uint32_t i; float f; } v; v.i = ((uint32_t)u) << 16; return v.f;
}
__device__ __forceinline__ uint16_t f2bf(float f) {
  union { float f; uint32_t i; } v; v.f = f;
  return (uint16_t)((v.i + 0x7FFFu + ((v.i >> 16) & 1u)) >> 16);  // RNE
}
__device__ __forceinline__ float fexp(float x) { return __builtin_amdgcn_exp2f(x * 1.44269504088896340736f); }
__device__ __forceinline__ float frcp(float x) { return __builtin_amdgcn_rcpf(x); }
__device__ __forceinline__ float fsig(float x)  { return frcp(1.f + fexp(-x)); }
__device__ __forceinline__ float ftanh(float x) { return 1.f - 2.f * frcp(1.f + fexp(2.f * x)); }

// ============================ conv stack ===================================
// Grid: (16 chunks of 64 cols, 512 t). Block 256 thr: lane=h (0..63), 4 waves
// split columns. LDS intermediates fp32, row stride 72 (16B-aligned, 4-way
// write aliasing max). Weights for phases 2-4 staged per-phase into wsh
// (layout [c][h*2..h*2+1], row stride 130 floats -> 2-way read aliasing).
// Column index il maps to global l: gl = l0 - 2 + il.
#define YSTR 72
#define WSTR 130
__global__ __launch_bounds__(256) void conv_stack_k(
    const float* __restrict__ inp,
    const float* __restrict__ w1p, const float* __restrict__ b1p,
    const float* __restrict__ g1p, const float* __restrict__ be1p,
    const float* __restrict__ m1p, const float* __restrict__ v1p,
    const float* __restrict__ w2p, const float* __restrict__ b2p,
    const float* __restrict__ g2p, const float* __restrict__ be2p,
    const float* __restrict__ m2p, const float* __restrict__ v2p,
    const float* __restrict__ t1p, const float* __restrict__ tb1p,
    const float* __restrict__ g3p, const float* __restrict__ be3p,
    const float* __restrict__ m3p, const float* __restrict__ v3p,
    const float* __restrict__ t2p, const float* __restrict__ tb2p,
    uint16_t* __restrict__ X)
{
  __shared__ float xs[6][YSTR];
  __shared__ float yA[65][YSTR];   // y1, later y3
  __shared__ float yB[65][YSTR];   // y2
  __shared__ float wsh[64][WSTR];  // per-phase weights [c][h*2+k]
  const int tid = threadIdx.x;
  const int h   = tid & 63;
  const int wv  = tid >> 6;
  const int t   = blockIdx.y;
  const int l0  = blockIdx.x * 64;

  // zero-init yA/yB so any boundary read is 0.0, never garbage
  for (int i = tid; i < 65 * YSTR; i += 256) { yA[0][i] = 0.f; yB[0][i] = 0.f; }

  // stage input window (full 6 x YSTR, masked-zero outside [0,1024))
  for (int i = tid; i < 6 * YSTR; i += 256) {
    int c = i % 6, il = i / 6;
    int gl = l0 - 2 + il;
    float v = 0.f;
    if (gl >= 0 && gl < 1024) v = inp[(size_t)t * 6144 + (size_t)gl * 6 + c];
    xs[c][il] = v;
  }

  // ---- phase 1: y1 = relu(bn1(conv1(x))), valid gl in [0,1023), cols il<67
  {
    float wr[12];
#pragma unroll
    for (int i = 0; i < 6; ++i) {
      float2 q = *(const float2*)(w1p + h * 12 + i * 2);
      wr[i * 2] = q.x; wr[i * 2 + 1] = q.y;
    }
    float sc = g1p[h] * __builtin_amdgcn_rsqf(v1p[h] + 1e-5f);
    float tc = (b1p[h] - m1p[h]) * sc + be1p[h];
    __syncthreads();   // covers zero-init + xs staging
    for (int base = wv * 4; base < 67; base += 16) {
      float a0 = 0, a1 = 0, a2 = 0, a3 = 0;
#pragma unroll
      for (int c = 0; c < 6; ++c) {
        float4 v = *(const float4*)&xs[c][base];
        float s4 = xs[c][base + 4];
        float k0 = wr[c * 2], k1 = wr[c * 2 + 1];
        a0 += v.x * k0 + v.y * k1;
        a1 += v.y * k0 + v.z * k1;
        a2 += v.z * k0 + v.w * k1;
        a3 += v.w * k0 + s4 * k1;
      }
      float r[4] = {a0, a1, a2, a3};
#pragma unroll
      for (int j = 0; j < 4; ++j) {
        int il = base + j;
        if (il < 67) {
          int gl = l0 - 2 + il;
          yA[h][il] = (gl >= 0 && gl < 1023) ? fmaxf(r[j] * sc + tc, 0.f) : 0.f;
        }
      }
    }
  }
  __syncthreads();

  // stage phase-2 weights: global w2p[h][c][k] -> wsh[c][h*2+k] (transpose)
  for (int i = tid; i < 4096; i += 256) {
    int hh = i >> 6, cc = i & 63;
    float2 q = *(const float2*)(w2p + (size_t)i * 2);   // = w2p[hh*128+cc*2]
    wsh[cc][hh * 2] = q.x; wsh[cc][hh * 2 + 1] = q.y;
  }
  __syncthreads();

  // ---- phase 2: y2 = relu(bn2(conv2(y1))), valid gl in [0,1022), cols il<66
  {
    float sc = g2p[h] * __builtin_amdgcn_rsqf(v2p[h] + 1e-5f);
    float tc = (b2p[h] - m2p[h]) * sc + be2p[h];
    for (int base = wv * 8; base < 66; base += 32) {
      float a[8] = {0, 0, 0, 0, 0, 0, 0, 0};
#pragma unroll
      for (int c = 0; c < 64; ++c) {
        float2 kk = *(const float2*)&wsh[c][h * 2];
        float4 v0 = *(const float4*)&yA[c][base];
        float4 v1 = *(const float4*)&yA[c][base + 4];
        float s8  = yA[c][base + 8];
        float k0 = kk.x, k1 = kk.y;
        a[0] += v0.x * k0 + v0.y * k1;
        a[1] += v0.y * k0 + v0.z * k1;
        a[2] += v0.z * k0 + v0.w * k1;
        a[3] += v0.w * k0 + v1.x * k1;
        a[4] += v1.x * k0 + v1.y * k1;
        a[5] += v1.y * k0 + v1.z * k1;
        a[6] += v1.z * k0 + v1.w * k1;
        a[7] += v1.w * k0 + s8   * k1;
      }
#pragma unroll
      for (int j = 0; j < 8; ++j) {
        int il = base + j;
        if (il < 66) {
          int gl = l0 - 2 + il;
          yB[h][il] = (gl >= 0 && gl < 1022) ? fmaxf(a[j] * sc + tc, 0.f) : 0.f;
        }
      }
    }
  }
  __syncthreads();

  // stage phase-3 weights: global t1p[c][h][k] -> wsh[c][h*2+k] (linear)
  for (int i = tid; i < 4096; i += 256) {
    int cc = i >> 6, hh = i & 63;
    float2 q = *(const float2*)(t1p + (size_t)i * 2);   // = t1p[cc*128+hh*2]
    wsh[cc][hh * 2] = q.x; wsh[cc][hh * 2 + 1] = q.y;
  }
  __syncthreads();

  // ---- phase 3: y3 = relu(bn3(convT1(y2))) : y3[l]=y2[l]*w0+y2[l-1]*w1
  //      valid gl in [0,1023), cols 1<=il<66 ; overwrites yA
  {
    float sc = g3p[h] * __builtin_amdgcn_rsqf(v3p[h] + 1e-5f);
    float tc = (tb1p[h] - m3p[h]) * sc + be3p[h];
    for (int base = wv * 8; base < 66; base += 32) {
      float a[8] = {0, 0, 0, 0, 0, 0, 0, 0};
#pragma unroll
      for (int c = 0; c < 64; ++c) {
        float2 kk = *(const float2*)&wsh[c][h * 2];
        float4 v0 = *(const float4*)&yB[c][base];
        float4 v1 = *(const float4*)&yB[c][base + 4];
        float sm  = (base > 0) ? yB[c][base - 1] : 0.f;
        float k0 = kk.x, k1 = kk.y;
        a[0] += v0.x * k0 + sm   * k1;
        a[1] += v0.y * k0 + v0.x * k1;
        a[2] += v0.z * k0 + v0.y * k1;
        a[3] += v0.w * k0 + v0.z * k1;
        a[4] += v1.x * k0 + v0.w * k1;
        a[5] += v1.y * k0 + v1.x * k1;
        a[6] += v1.z * k0 + v1.y * k1;
        a[7] += v1.w * k0 + v1.z * k1;
      }
#pragma unroll
      for (int j = 0; j < 8; ++j) {
        int il = base + j;
        if (il >= 1 && il < 66) {
          int gl = l0 - 2 + il;
          yA[h][il] = (gl >= 0 && gl < 1023) ? fmaxf(a[j] * sc + tc, 0.f) : 0.f;
        }
      }
    }
  }
  __syncthreads();

  // stage phase-4 weights: global t2p[c][h][k] -> wsh[c][h*2+k] (linear)
  for (int i = tid; i < 4096; i += 256) {
    int cc = i >> 6, hh = i & 63;
    float2 q = *(const float2*)(t2p + (size_t)i * 2);
    wsh[cc][hh * 2] = q.x; wsh[cc][hh * 2 + 1] = q.y;
  }
  __syncthreads();

  // ---- phase 4: y4 = relu(convT2(y3)+b) ; cols 2<=il<66 -> gl in [l0,l0+64)
  //      store transposed (bf16) to X slot t+1 : X[(t+1)][gl][h]
  {
    float tb = tb2p[h];
    for (int base = wv * 8; base < 66; base += 32) {
      float a[8] = {0, 0, 0, 0, 0, 0, 0, 0};
#pragma unroll
      for (int c = 0; c < 64; ++c) {
        float2 kk = *(const float2*)&wsh[c][h * 2];
        float4 v0 = *(const float4*)&yA[c][base];
        float4 v1 = *(const float4*)&yA[c][base + 4];
        float sm  = (base > 0) ? yA[c][base - 1] : 0.f;
        float k0 = kk.x, k1 = kk.y;
        a[0] += v0.x * k0 + sm   * k1;
        a[1] += v0.y * k0 + v0.x * k1;
        a[2] += v0.z * k0 + v0.y * k1;
        a[3] += v0.w * k0 + v0.z * k1;
        a[4] += v1.x * k0 + v0.w * k1;
        a[5] += v1.y * k0 + v1.x * k1;
        a[6] += v1.z * k0 + v1.y * k1;
        a[7] += v1.w * k0 + v1.z * k1;
      }
#pragma unroll
      for (int j = 0; j < 8; ++j) {
        int il = base + j;
        if (il >= 2 && il < 66) {
          int gl = l0 - 2 + il;
          X[(size_t)(t + 1) * 65536 + (size_t)gl * 64 + h] = f2bf(fmaxf(a[j] + tb, 0.f));
        }
      }
    }
  }
}

// ============================== LSTM =======================================
// 64 blocks x 16 batch rows; 4 waves; wave w owns gate cols {16w,+64,+128,+192}
// so each lane holds i,f,g,o of its cells. K=128 = [x_t | h] via 4 MFMA chunks.
// h exchanged through double-buffered LDS (row stride 72 -> only 2-way bank
// aliasing, free). One __syncthreads per step.
#define HSTR 72
#define MFMA16(a, b, c) __builtin_amdgcn_mfma_f32_16x16x32_bf16(a, b, c, 0, 0, 0)

#define LSTM_STEP(T_, XC, XN, BR, BW) do {                                     \
    if ((T_) + 1 < 512) {                                                      \
      const uint16_t* xp_ = Xb + (size_t)((T_) + 2) * 65536                    \
                          + (size_t)(l0 + (lane & 15)) * 64 + kgrp;            \
      XN[0] = *(const bf16x8*)xp_;                                             \
      XN[1] = *(const bf16x8*)(xp_ + 32);                                      \
    }                                                                          \
    bf16x8 hf0_ = *(const bf16x8*)&hl[BR][(lane & 15) * HSTR + kgrp];          \
    bf16x8 hf1_ = *(const bf16x8*)&hl[BR][(lane & 15) * HSTR + 32 + kgrp];     \
    f32x4 ai_ = Z4, af_ = Z4, ag_ = Z4, ao_ = Z4;                              \
    ai_ = MFMA16(XC[0], bfr[0][0], ai_); af_ = MFMA16(XC[0], bfr[1][0], af_);  \
    ag_ = MFMA16(XC[0], bfr[2][0], ag_); ao_ = MFMA16(XC[0], bfr[3][0], ao_);  \
    ai_ = MFMA16(XC[1], bfr[0][1], ai_); af_ = MFMA16(XC[1], bfr[1][1], af_);  \
    ag_ = MFMA16(XC[1], bfr[2][1], ag_); ao_ = MFMA16(XC[1], bfr[3][1], ao_);  \
    ai_ = MFMA16(hf0_,  bfr[0][2], ai_); af_ = MFMA16(hf0_,  bfr[1][2], af_);  \
    ag_ = MFMA16(hf0_,  bfr[2][2], ag_); ao_ = MFMA16(hf0_,  bfr[3][2], ao_);  \
    ai_ = MFMA16(hf1_,  bfr[0][3], ai_); af_ = MFMA16(hf1_,  bfr[1][3], af_);  \
    ag_ = MFMA16(hf1_,  bfr[2][3], ag_); ao_ = MFMA16(hf1_,  bfr[3][3], ao_);  \
    _Pragma("unroll")                                                          \
    for (int r_ = 0; r_ < 4; ++r_) {                                           \
      float ii = fsig(ai_[r_] + bi0);                                          \
      float ff = fsig(af_[r_] + bi1);                                          \
      float gg = ftanh(ag_[r_] + bi2);                                         \
      float oo = fsig(ao_[r_] + bi3);                                          \
      creg[r_] = ff * creg[r_] + ii * gg;                                      \
      hprev[r_] = oo * ftanh(creg[r_]);                                        \
      uint16_t hb_ = f2bf(hprev[r_]);                                          \
      hl[BW][(r0 + r_) * HSTR + hcol] = hb_;                                   \
      Xb[(size_t)(T_) * 65536 + (size_t)(l0 + r0 + r_) * 64 + hcol] = hb_;     \
    }                                                                          \
    __syncthreads();                                                           \
  } while (0)

__global__ __launch_bounds__(256) void lstm_k(
    const float* __restrict__ h0p, const float* __restrict__ c0p,
    const float* __restrict__ wihp, const float* __restrict__ whhp,
    const float* __restrict__ bihp, const float* __restrict__ bhhp,
    uint16_t* __restrict__ Xb, float* __restrict__ outp)
{
  __shared__ __align__(16) uint16_t hl[2][16 * HSTR];
  const int tid  = threadIdx.x;
  const int lane = tid & 63;
  const int wv   = tid >> 6;
  const int l0   = blockIdx.x << 4;
  const int hcol = (wv << 4) | (lane & 15);
  const int r0   = (lane >> 4) << 2;
  const int kgrp = (lane >> 4) << 3;

  // B fragments (loop-invariant, registers): B[k][n], k<64: w_ih, else w_hh
  bf16x8 bfr[4][4];
#pragma unroll
  for (int nt = 0; nt < 4; ++nt) {
    int n = nt * 64 + hcol;
#pragma unroll
    for (int kc = 0; kc < 4; ++kc) {
      int k0 = kc * 32 + kgrp;
      const float* src = (k0 < 64) ? (wihp + (size_t)n * 64 + k0)
                                   : (whhp + (size_t)n * 64 + (k0 - 64));
      bf16x8 f;
#pragma unroll
      for (int j = 0; j < 8; ++j) f[j] = (short)f2bf(src[j]);
      bfr[nt][kc] = f;
    }
  }
  float bi0 = bihp[hcol]       + bhhp[hcol];
  float bi1 = bihp[64 + hcol]  + bhhp[64 + hcol];
  float bi2 = bihp[128 + hcol] + bhhp[128 + hcol];
  float bi3 = bihp[192 + hcol] + bhhp[192 + hcol];

  float creg[4], hprev[4] = {0.f, 0.f, 0.f, 0.f};
#pragma unroll
  for (int r = 0; r < 4; ++r)
    creg[r] = c0p[(size_t)(l0 + r0 + r) * 64 + hcol];

  // init h LDS buf 0 from hidden_state (fp32 -> bf16)
  {
    int row = tid >> 4, col = (tid & 15) << 2;
    const float* sp = h0p + (size_t)(l0 + row) * 64 + col;
    int b = row * HSTR + col;
    hl[0][b]     = f2bf(sp[0]); hl[0][b + 1] = f2bf(sp[1]);
    hl[0][b + 2] = f2bf(sp[2]); hl[0][b + 3] = f2bf(sp[3]);
  }

  bf16x8 xA[2], xB[2];
  {
    const uint16_t* xp = Xb + 65536 + (size_t)(l0 + (lane & 15)) * 64 + kgrp;
    xA[0] = *(const bf16x8*)xp;
    xA[1] = *(const bf16x8*)(xp + 32);
  }
  __syncthreads();

  const f32x4 Z4 = {0.f, 0.f, 0.f, 0.f};
#pragma unroll 1
  for (int t2 = 0; t2 < 512; t2 += 2) {
    LSTM_STEP(t2,     xA, xB, 0, 1);
    LSTM_STEP(t2 + 1, xB, xA, 1, 0);
  }

  // hT at out+524288, cT at out+589824 (fp32)
#pragma unroll
  for (int r = 0; r < 4; ++r) {
    int gr = l0 + r0 + r;
    outp[524288 + (size_t)gr * 64 + hcol] = hprev[r];
    outp[589824 + (size_t)gr * 64 + hcol] = creg[r];
  }
}

// ========================= output projection ===============================
__global__ __launch_bounds__(256) void proj_k(
    const uint16_t* __restrict__ Hb, const float* __restrict__ owp,
    const float* __restrict__ obp, float* __restrict__ outp)
{
  __shared__ float ows[64];
  if (threadIdx.x < 64) ows[threadIdx.x] = owp[threadIdx.x];
  __syncthreads();
  int idx = blockIdx.x * 256 + threadIdx.x;     // = t*1024 + l
  const uint16_t* hp = Hb + (size_t)idx * 64;   // slot t, row l
  float s = obp[0];
#pragma unroll
  for (int j = 0; j < 8; ++j) {
    bf16x8 hv = *(const bf16x8*)(hp + j * 8);
#pragma unroll
    for (int e = 0; e < 8; ++e) s += bf2f((uint16_t)hv[e]) * ows[j * 8 + e];
  }
  outp[idx] = s;
}

// ============================== launch =====================================
extern "C" void kernel_launch(void* const* d_in, const int* in_sizes, int n_in,
                              void* d_out, int out_size, void* d_ws, size_t ws_size,
                              hipStream_t stream)
{
  (void)in_sizes; (void)n_in; (void)out_size;
  if (ws_size < (size_t)513 * 65536 * 2) return;   // ws guard

  const float* inp = (const float*)d_in[0];
  const float* h0p = (const float*)d_in[1];
  const float* c0p = (const float*)d_in[2];
  const float* w1  = (const float*)d_in[3];
  const float* b1  = (const float*)d_in[4];
  const float* g1  = (const float*)d_in[5];
  const float* be1 = (const float*)d_in[6];
  const float* m1  = (const float*)d_in[7];
  const float* v1  = (const float*)d_in[8];
  const float* w2  = (const float*)d_in[9];
  const float* b2  = (const float*)d_in[10];
  const float* g2  = (const float*)d_in[11];
  const float* be2 = (const float*)d_in[12];
  const float* m2  = (const float*)d_in[13];
  const float* v2  = (const float*)d_in[14];
  const float* tw1 = (const float*)d_in[15];
  const float* tb1 = (const float*)d_in[16];
  const float* g3  = (const float*)d_in[17];
  const float* be3 = (const float*)d_in[18];
  const float* m3  = (const float*)d_in[19];
  const float* v3  = (const float*)d_in[20];
  const float* tw2 = (const float*)d_in[21];
  const float* tb2 = (const float*)d_in[22];
  const float* wih = (const float*)d_in[23];
  const float* whh = (const float*)d_in[24];
  const float* bih = (const float*)d_in[25];
  const float* bhh = (const float*)d_in[26];
  const float* ow  = (const float*)d_in[27];
  const float* ob  = (const float*)d_in[28];

  uint16_t* Xb   = (uint16_t*)d_ws;
  float*    outp = (float*)d_out;

  conv_stack_k<<<dim3(16, 512), 256, 0, stream>>>(
      inp, w1, b1, g1, be1, m1, v1, w2, b2, g2, be2, m2, v2,
      tw1, tb1, g3, be3, m3, v3, tw2, tb2, Xb);
  lstm_k<<<64, 256, 0, stream>>>(h0p, c0p, wih, whh, bih, bhh, Xb, outp);
  proj_k<<<2048, 256, 0, stream>>>(Xb, ow, ob, outp);
}

// Round 5
// 1228.194 us; speedup vs baseline: 14.5421x; 10.0373x over previous
//
#include <hip/hip_runtime.h>
#include <hip/hip_bf16.h>
#include <stdint.h>

// ---------------------------------------------------------------------------
// CNNLSTM: conv1(6->64,k2) BN ReLU -> conv2(64->64,k2) BN ReLU ->
//          convT1(64->64,k2) BN ReLU -> convT2(64->64,k2) ReLU ->
//          LSTM(T=512, batch=1024, H=64) -> linear(64->1)
// Device I/O: FP32. Internal: conv fp32, weights in LDS, unroll controlled
// (round-4 full unroll of base+c loops spilled: VGPR=256, 23.9 GB scratch);
// LSTM MFMA bf16 with fp32 accum/cell; outputs fp32.
// ws layout: 513 slots of 1024*64 bf16 (slot s = ws + s*65536 elems).
//   conv writes x_t to slot t+1 ; LSTM reads slot t+1, writes h_t to slot t ;
//   projection reads h_t at slot t.  ws bytes needed: 513*65536*2 = 67,239,936.
// ---------------------------------------------------------------------------

typedef __attribute__((ext_vector_type(8))) short bf16x8;
typedef __attribute__((ext_vector_type(4))) float f32x4;

__device__ __forceinline__ float bf2f(uint16_t u) {
  union { uint32_t i; float f; } v; v.i = ((uint32_t)u) << 16; return v.f;
}
__device__ __forceinline__ uint16_t f2bf(float f) {
  union { float f; uint32_t i; } v; v.f = f;
  return (uint16_t)((v.i + 0x7FFFu + ((v.i >> 16) & 1u)) >> 16);  // RNE
}
__device__ __forceinline__ float fexp(float x) { return __builtin_amdgcn_exp2f(x * 1.44269504088896340736f); }
__device__ __forceinline__ float frcp(float x) { return __builtin_amdgcn_rcpf(x); }
__device__ __forceinline__ float fsig(float x)  { return frcp(1.f + fexp(-x)); }
__device__ __forceinline__ float ftanh(float x) { return 1.f - 2.f * frcp(1.f + fexp(2.f * x)); }

// ============================ conv stack ===================================
// Grid: (16 chunks of 64 cols, 512 t). Block 256 thr: lane=h (0..63), 4 waves
// split columns. LDS intermediates fp32, row stride 72. Weights for phases
// 2-4 staged per-phase into wsh [c][h*2+k], row stride 130.
// base loops: unroll 1 (wave-dependent trip count; full unroll was the spill
// source). c loops: unroll 4 (ILP without pressure blowup).
#define YSTR 72
#define WSTR 130
__global__ __launch_bounds__(256, 2) void conv_stack_k(
    const float* __restrict__ inp,
    const float* __restrict__ w1p, const float* __restrict__ b1p,
    const float* __restrict__ g1p, const float* __restrict__ be1p,
    const float* __restrict__ m1p, const float* __restrict__ v1p,
    const float* __restrict__ w2p, const float* __restrict__ b2p,
    const float* __restrict__ g2p, const float* __restrict__ be2p,
    const float* __restrict__ m2p, const float* __restrict__ v2p,
    const float* __restrict__ t1p, const float* __restrict__ tb1p,
    const float* __restrict__ g3p, const float* __restrict__ be3p,
    const float* __restrict__ m3p, const float* __restrict__ v3p,
    const float* __restrict__ t2p, const float* __restrict__ tb2p,
    uint16_t* __restrict__ X)
{
  __shared__ float xs[6][YSTR];
  __shared__ float yA[65][YSTR];   // y1, later y3
  __shared__ float yB[65][YSTR];   // y2
  __shared__ float wsh[64][WSTR];  // per-phase weights [c][h*2+k]
  const int tid = threadIdx.x;
  const int h   = tid & 63;
  const int wv  = tid >> 6;
  const int t   = blockIdx.y;
  const int l0  = blockIdx.x * 64;

  // zero-init yA/yB so any boundary read is 0.0, never garbage
  for (int i = tid; i < 65 * YSTR; i += 256) { yA[0][i] = 0.f; yB[0][i] = 0.f; }

  // stage input window (full 6 x YSTR, masked-zero outside [0,1024))
  for (int i = tid; i < 6 * YSTR; i += 256) {
    int c = i % 6, il = i / 6;
    int gl = l0 - 2 + il;
    float v = 0.f;
    if (gl >= 0 && gl < 1024) v = inp[(size_t)t * 6144 + (size_t)gl * 6 + c];
    xs[c][il] = v;
  }

  // ---- phase 1: y1 = relu(bn1(conv1(x))), valid gl in [0,1023), cols il<67
  {
    float wr[12];
#pragma unroll
    for (int i = 0; i < 6; ++i) {
      float2 q = *(const float2*)(w1p + h * 12 + i * 2);
      wr[i * 2] = q.x; wr[i * 2 + 1] = q.y;
    }
    float sc = g1p[h] * __builtin_amdgcn_rsqf(v1p[h] + 1e-5f);
    float tc = (b1p[h] - m1p[h]) * sc + be1p[h];
    __syncthreads();   // covers zero-init + xs staging
#pragma unroll 1
    for (int base = wv * 4; base < 67; base += 16) {
      float a0 = 0, a1 = 0, a2 = 0, a3 = 0;
#pragma unroll
      for (int c = 0; c < 6; ++c) {
        float4 v = *(const float4*)&xs[c][base];
        float s4 = xs[c][base + 4];
        float k0 = wr[c * 2], k1 = wr[c * 2 + 1];
        a0 += v.x * k0 + v.y * k1;
        a1 += v.y * k0 + v.z * k1;
        a2 += v.z * k0 + v.w * k1;
        a3 += v.w * k0 + s4 * k1;
      }
      float r[4] = {a0, a1, a2, a3};
#pragma unroll
      for (int j = 0; j < 4; ++j) {
        int il = base + j;
        if (il < 67) {
          int gl = l0 - 2 + il;
          yA[h][il] = (gl >= 0 && gl < 1023) ? fmaxf(r[j] * sc + tc, 0.f) : 0.f;
        }
      }
    }
  }
  __syncthreads();

  // stage phase-2 weights: global w2p[h][c][k] -> wsh[c][h*2+k] (transpose)
  for (int i = tid; i < 4096; i += 256) {
    int hh = i >> 6, cc = i & 63;
    float2 q = *(const float2*)(w2p + (size_t)i * 2);   // = w2p[hh*128+cc*2]
    wsh[cc][hh * 2] = q.x; wsh[cc][hh * 2 + 1] = q.y;
  }
  __syncthreads();

  // ---- phase 2: y2 = relu(bn2(conv2(y1))), valid gl in [0,1022), cols il<66
  {
    float sc = g2p[h] * __builtin_amdgcn_rsqf(v2p[h] + 1e-5f);
    float tc = (b2p[h] - m2p[h]) * sc + be2p[h];
#pragma unroll 1
    for (int base = wv * 8; base < 66; base += 32) {
      float a[8] = {0, 0, 0, 0, 0, 0, 0, 0};
#pragma unroll 4
      for (int c = 0; c < 64; ++c) {
        float2 kk = *(const float2*)&wsh[c][h * 2];
        float4 v0 = *(const float4*)&yA[c][base];
        float4 v1 = *(const float4*)&yA[c][base + 4];
        float s8  = yA[c][base + 8];
        float k0 = kk.x, k1 = kk.y;
        a[0] += v0.x * k0 + v0.y * k1;
        a[1] += v0.y * k0 + v0.z * k1;
        a[2] += v0.z * k0 + v0.w * k1;
        a[3] += v0.w * k0 + v1.x * k1;
        a[4] += v1.x * k0 + v1.y * k1;
        a[5] += v1.y * k0 + v1.z * k1;
        a[6] += v1.z * k0 + v1.w * k1;
        a[7] += v1.w * k0 + s8   * k1;
      }
#pragma unroll
      for (int j = 0; j < 8; ++j) {
        int il = base + j;
        if (il < 66) {
          int gl = l0 - 2 + il;
          yB[h][il] = (gl >= 0 && gl < 1022) ? fmaxf(a[j] * sc + tc, 0.f) : 0.f;
        }
      }
    }
  }
  __syncthreads();

  // stage phase-3 weights: global t1p[c][h][k] -> wsh[c][h*2+k] (linear)
  for (int i = tid; i < 4096; i += 256) {
    int cc = i >> 6, hh = i & 63;
    float2 q = *(const float2*)(t1p + (size_t)i * 2);   // = t1p[cc*128+hh*2]
    wsh[cc][hh * 2] = q.x; wsh[cc][hh * 2 + 1] = q.y;
  }
  __syncthreads();

  // ---- phase 3: y3 = relu(bn3(convT1(y2))) : y3[l]=y2[l]*w0+y2[l-1]*w1
  //      valid gl in [0,1023), cols 1<=il<66 ; overwrites yA
  {
    float sc = g3p[h] * __builtin_amdgcn_rsqf(v3p[h] + 1e-5f);
    float tc = (tb1p[h] - m3p[h]) * sc + be3p[h];
#pragma unroll 1
    for (int base = wv * 8; base < 66; base += 32) {
      float a[8] = {0, 0, 0, 0, 0, 0, 0, 0};
#pragma unroll 4
      for (int c = 0; c < 64; ++c) {
        float2 kk = *(const float2*)&wsh[c][h * 2];
        float4 v0 = *(const float4*)&yB[c][base];
        float4 v1 = *(const float4*)&yB[c][base + 4];
        float sm  = (base > 0) ? yB[c][base - 1] : 0.f;
        float k0 = kk.x, k1 = kk.y;
        a[0] += v0.x * k0 + sm   * k1;
        a[1] += v0.y * k0 + v0.x * k1;
        a[2] += v0.z * k0 + v0.y * k1;
        a[3] += v0.w * k0 + v0.z * k1;
        a[4] += v1.x * k0 + v0.w * k1;
        a[5] += v1.y * k0 + v1.x * k1;
        a[6] += v1.z * k0 + v1.y * k1;
        a[7] += v1.w * k0 + v1.z * k1;
      }
#pragma unroll
      for (int j = 0; j < 8; ++j) {
        int il = base + j;
        if (il >= 1 && il < 66) {
          int gl = l0 - 2 + il;
          yA[h][il] = (gl >= 0 && gl < 1023) ? fmaxf(a[j] * sc + tc, 0.f) : 0.f;
        }
      }
    }
  }
  __syncthreads();

  // stage phase-4 weights: global t2p[c][h][k] -> wsh[c][h*2+k] (linear)
  for (int i = tid; i < 4096; i += 256) {
    int cc = i >> 6, hh = i & 63;
    float2 q = *(const float2*)(t2p + (size_t)i * 2);
    wsh[cc][hh * 2] = q.x; wsh[cc][hh * 2 + 1] = q.y;
  }
  __syncthreads();

  // ---- phase 4: y4 = relu(convT2(y3)+b) ; cols 2<=il<66 -> gl in [l0,l0+64)
  //      store transposed (bf16) to X slot t+1 : X[(t+1)][gl][h]
  {
    float tb = tb2p[h];
#pragma unroll 1
    for (int base = wv * 8; base < 66; base += 32) {
      float a[8] = {0, 0, 0, 0, 0, 0, 0, 0};
#pragma unroll 4
      for (int c = 0; c < 64; ++c) {
        float2 kk = *(const float2*)&wsh[c][h * 2];
        float4 v0 = *(const float4*)&yA[c][base];
        float4 v1 = *(const float4*)&yA[c][base + 4];
        float sm  = (base > 0) ? yA[c][base - 1] : 0.f;
        float k0 = kk.x, k1 = kk.y;
        a[0] += v0.x * k0 + sm   * k1;
        a[1] += v0.y * k0 + v0.x * k1;
        a[2] += v0.z * k0 + v0.y * k1;
        a[3] += v0.w * k0 + v0.z * k1;
        a[4] += v1.x * k0 + v0.w * k1;
        a[5] += v1.y * k0 + v1.x * k1;
        a[6] += v1.z * k0 + v1.y * k1;
        a[7] += v1.w * k0 + v1.z * k1;
      }
#pragma unroll
      for (int j = 0; j < 8; ++j) {
        int il = base + j;
        if (il >= 2 && il < 66) {
          int gl = l0 - 2 + il;
          X[(size_t)(t + 1) * 65536 + (size_t)gl * 64 + h] = f2bf(fmaxf(a[j] + tb, 0.f));
        }
      }
    }
  }
}

// ============================== LSTM =======================================
// 64 blocks x 16 batch rows; 4 waves; wave w owns gate cols {16w,+64,+128,+192}
// so each lane holds i,f,g,o of its cells. K=128 = [x_t | h] via 4 MFMA chunks.
// h exchanged through double-buffered LDS (row stride 72 -> only 2-way bank
// aliasing, free). One __syncthreads per step.
#define HSTR 72
#define MFMA16(a, b, c) __builtin_amdgcn_mfma_f32_16x16x32_bf16(a, b, c, 0, 0, 0)

#define LSTM_STEP(T_, XC, XN, BR, BW) do {                                     \
    if ((T_) + 1 < 512) {                                                      \
      const uint16_t* xp_ = Xb + (size_t)((T_) + 2) * 65536                    \
                          + (size_t)(l0 + (lane & 15)) * 64 + kgrp;            \
      XN[0] = *(const bf16x8*)xp_;                                             \
      XN[1] = *(const bf16x8*)(xp_ + 32);                                      \
    }                                                                          \
    bf16x8 hf0_ = *(const bf16x8*)&hl[BR][(lane & 15) * HSTR + kgrp];          \
    bf16x8 hf1_ = *(const bf16x8*)&hl[BR][(lane & 15) * HSTR + 32 + kgrp];     \
    f32x4 ai_ = Z4, af_ = Z4, ag_ = Z4, ao_ = Z4;                              \
    ai_ = MFMA16(XC[0], bfr[0][0], ai_); af_ = MFMA16(XC[0], bfr[1][0], af_);  \
    ag_ = MFMA16(XC[0], bfr[2][0], ag_); ao_ = MFMA16(XC[0], bfr[3][0], ao_);  \
    ai_ = MFMA16(XC[1], bfr[0][1], ai_); af_ = MFMA16(XC[1], bfr[1][1], af_);  \
    ag_ = MFMA16(XC[1], bfr[2][1], ag_); ao_ = MFMA16(XC[1], bfr[3][1], ao_);  \
    ai_ = MFMA16(hf0_,  bfr[0][2], ai_); af_ = MFMA16(hf0_,  bfr[1][2], af_);  \
    ag_ = MFMA16(hf0_,  bfr[2][2], ag_); ao_ = MFMA16(hf0_,  bfr[3][2], ao_);  \
    ai_ = MFMA16(hf1_,  bfr[0][3], ai_); af_ = MFMA16(hf1_,  bfr[1][3], af_);  \
    ag_ = MFMA16(hf1_,  bfr[2][3], ag_); ao_ = MFMA16(hf1_,  bfr[3][3], ao_);  \
    _Pragma("unroll")                                                          \
    for (int r_ = 0; r_ < 4; ++r_) {                                           \
      float ii = fsig(ai_[r_] + bi0);                                          \
      float ff = fsig(af_[r_] + bi1);                                          \
      float gg = ftanh(ag_[r_] + bi2);                                         \
      float oo = fsig(ao_[r_] + bi3);                                          \
      creg[r_] = ff * creg[r_] + ii * gg;                                      \
      hprev[r_] = oo * ftanh(creg[r_]);                                        \
      uint16_t hb_ = f2bf(hprev[r_]);                                          \
      hl[BW][(r0 + r_) * HSTR + hcol] = hb_;                                   \
      Xb[(size_t)(T_) * 65536 + (size_t)(l0 + r0 + r_) * 64 + hcol] = hb_;     \
    }                                                                          \
    __syncthreads();                                                           \
  } while (0)

__global__ __launch_bounds__(256) void lstm_k(
    const float* __restrict__ h0p, const float* __restrict__ c0p,
    const float* __restrict__ wihp, const float* __restrict__ whhp,
    const float* __restrict__ bihp, const float* __restrict__ bhhp,
    uint16_t* __restrict__ Xb, float* __restrict__ outp)
{
  __shared__ __align__(16) uint16_t hl[2][16 * HSTR];
  const int tid  = threadIdx.x;
  const int lane = tid & 63;
  const int wv   = tid >> 6;
  const int l0   = blockIdx.x << 4;
  const int hcol = (wv << 4) | (lane & 15);
  const int r0   = (lane >> 4) << 2;
  const int kgrp = (lane >> 4) << 3;

  // B fragments (loop-invariant, registers): B[k][n], k<64: w_ih, else w_hh
  bf16x8 bfr[4][4];
#pragma unroll
  for (int nt = 0; nt < 4; ++nt) {
    int n = nt * 64 + hcol;
#pragma unroll
    for (int kc = 0; kc < 4; ++kc) {
      int k0 = kc * 32 + kgrp;
      const float* src = (k0 < 64) ? (wihp + (size_t)n * 64 + k0)
                                   : (whhp + (size_t)n * 64 + (k0 - 64));
      bf16x8 f;
#pragma unroll
      for (int j = 0; j < 8; ++j) f[j] = (short)f2bf(src[j]);
      bfr[nt][kc] = f;
    }
  }
  float bi0 = bihp[hcol]       + bhhp[hcol];
  float bi1 = bihp[64 + hcol]  + bhhp[64 + hcol];
  float bi2 = bihp[128 + hcol] + bhhp[128 + hcol];
  float bi3 = bihp[192 + hcol] + bhhp[192 + hcol];

  float creg[4], hprev[4] = {0.f, 0.f, 0.f, 0.f};
#pragma unroll
  for (int r = 0; r < 4; ++r)
    creg[r] = c0p[(size_t)(l0 + r0 + r) * 64 + hcol];

  // init h LDS buf 0 from hidden_state (fp32 -> bf16)
  {
    int row = tid >> 4, col = (tid & 15) << 2;
    const float* sp = h0p + (size_t)(l0 + row) * 64 + col;
    int b = row * HSTR + col;
    hl[0][b]     = f2bf(sp[0]); hl[0][b + 1] = f2bf(sp[1]);
    hl[0][b + 2] = f2bf(sp[2]); hl[0][b + 3] = f2bf(sp[3]);
  }

  bf16x8 xA[2], xB[2];
  {
    const uint16_t* xp = Xb + 65536 + (size_t)(l0 + (lane & 15)) * 64 + kgrp;
    xA[0] = *(const bf16x8*)xp;
    xA[1] = *(const bf16x8*)(xp + 32);
  }
  __syncthreads();

  const f32x4 Z4 = {0.f, 0.f, 0.f, 0.f};
#pragma unroll 1
  for (int t2 = 0; t2 < 512; t2 += 2) {
    LSTM_STEP(t2,     xA, xB, 0, 1);
    LSTM_STEP(t2 + 1, xB, xA, 1, 0);
  }

  // hT at out+524288, cT at out+589824 (fp32)
#pragma unroll
  for (int r = 0; r < 4; ++r) {
    int gr = l0 + r0 + r;
    outp[524288 + (size_t)gr * 64 + hcol] = hprev[r];
    outp[589824 + (size_t)gr * 64 + hcol] = creg[r];
  }
}

// ========================= output projection ===============================
__global__ __launch_bounds__(256) void proj_k(
    const uint16_t* __restrict__ Hb, const float* __restrict__ owp,
    const float* __restrict__ obp, float* __restrict__ outp)
{
  __shared__ float ows[64];
  if (threadIdx.x < 64) ows[threadIdx.x] = owp[threadIdx.x];
  __syncthreads();
  int idx = blockIdx.x * 256 + threadIdx.x;     // = t*1024 + l
  const uint16_t* hp = Hb + (size_t)idx * 64;   // slot t, row l
  float s = obp[0];
#pragma unroll
  for (int j = 0; j < 8; ++j) {
    bf16x8 hv = *(const bf16x8*)(hp + j * 8);
#pragma unroll
    for (int e = 0; e < 8; ++e) s += bf2f((uint16_t)hv[e]) * ows[j * 8 + e];
  }
  outp[idx] = s;
}

// ============================== launch =====================================
extern "C" void kernel_launch(void* const* d_in, const int* in_sizes, int n_in,
                              void* d_out, int out_size, void* d_ws, size_t ws_size,
                              hipStream_t stream)
{
  (void)in_sizes; (void)n_in; (void)out_size;
  if (ws_size < (size_t)513 * 65536 * 2) return;   // ws guard

  const float* inp = (const float*)d_in[0];
  const float* h0p = (const float*)d_in[1];
  const float* c0p = (const float*)d_in[2];
  const float* w1  = (const float*)d_in[3];
  const float* b1  = (const float*)d_in[4];
  const float* g1  = (const float*)d_in[5];
  const float* be1 = (const float*)d_in[6];
  const float* m1  = (const float*)d_in[7];
  const float* v1  = (const float*)d_in[8];
  const float* w2  = (const float*)d_in[9];
  const float* b2  = (const float*)d_in[10];
  const float* g2  = (const float*)d_in[11];
  const float* be2 = (const float*)d_in[12];
  const float* m2  = (const float*)d_in[13];
  const float* v2  = (const float*)d_in[14];
  const float* tw1 = (const float*)d_in[15];
  const float* tb1 = (const float*)d_in[16];
  const float* g3  = (const float*)d_in[17];
  const float* be3 = (const float*)d_in[18];
  const float* m3  = (const float*)d_in[19];
  const float* v3  = (const float*)d_in[20];
  const float* tw2 = (const float*)d_in[21];
  const float* tb2 = (const float*)d_in[22];
  const float* wih = (const float*)d_in[23];
  const float* whh = (const float*)d_in[24];
  const float* bih = (const float*)d_in[25];
  const float* bhh = (const float*)d_in[26];
  const float* ow  = (const float*)d_in[27];
  const float* ob  = (const float*)d_in[28];

  uint16_t* Xb   = (uint16_t*)d_ws;
  float*    outp = (float*)d_out;

  conv_stack_k<<<dim3(16, 512), 256, 0, stream>>>(
      inp, w1, b1, g1, be1, m1, v1, w2, b2, g2, be2, m2, v2,
      tw1, tb1, g3, be3, m3, v3, tw2, tb2, Xb);
  lstm_k<<<64, 256, 0, stream>>>(h0p, c0p, wih, whh, bih, bhh, Xb, outp);
  proj_k<<<2048, 256, 0, stream>>>(Xb, ow, ob, outp);
}

// Round 6
// 478.422 us; speedup vs baseline: 37.3321x; 2.5672x over previous
//
#include <hip/hip_runtime.h>
#include <hip/hip_bf16.h>
#include <stdint.h>

// ---------------------------------------------------------------------------
// CNNLSTM: conv1(6->64,k2) BN ReLU -> conv2(64->64,k2) BN ReLU ->
//          convT1(64->64,k2) BN ReLU -> convT2(64->64,k2) ReLU ->
//          LSTM(T=512, batch=1024, H=64) -> linear(64->1)
// Device I/O: FP32. Conv phases 2-4 run on MFMA (bf16 in, fp32 accum):
// each is a 64x64xK=128 matmul  out[h][l] = sum_{c,k} W[h][k*64+c] * y[c][l+d(k)]
// with the tap d(k) folded into the B-operand row offset. Phase 1 (K=6) VALU.
// y tiles live transposed in LDS: yT[row = il+1][c] bf16, stride 72
//   (row 0 == il=-1 stays zero -> convT's l-1 tap needs no masking).
// ws layout: 513 slots of 1024*64 bf16 (slot s = ws + s*65536 elems).
//   conv writes x_t to slot t+1 ; LSTM reads slot t+1, writes h_t to slot t ;
//   projection reads h_t at slot t.  ws bytes: 513*65536*2 = 67,239,936.
// ---------------------------------------------------------------------------

typedef __attribute__((ext_vector_type(8))) short bf16x8;
typedef __attribute__((ext_vector_type(4))) float f32x4;

__device__ __forceinline__ float bf2f(uint16_t u) {
  union { uint32_t i; float f; } v; v.i = ((uint32_t)u) << 16; return v.f;
}
__device__ __forceinline__ uint16_t f2bf(float f) {
  union { float f; uint32_t i; } v; v.f = f;
  return (uint16_t)((v.i + 0x7FFFu + ((v.i >> 16) & 1u)) >> 16);  // RNE
}
__device__ __forceinline__ float fexp(float x) { return __builtin_amdgcn_exp2f(x * 1.44269504088896340736f); }
__device__ __forceinline__ float frcp(float x) { return __builtin_amdgcn_rcpf(x); }
__device__ __forceinline__ float fsig(float x)  { return frcp(1.f + fexp(-x)); }
__device__ __forceinline__ float ftanh(float x) { return 1.f - 2.f * frcp(1.f + fexp(2.f * x)); }

#define MFMA16(a, b, c) __builtin_amdgcn_mfma_f32_16x16x32_bf16(a, b, c, 0, 0, 0)

// ============================ conv stack ===================================
// Grid: (16 chunks of 64 cols, 512 t). Block 256 thr = 4 waves.
// il -> global l: gl = l0 - 2 + il. yT row = il + 1.
#define YT   72      // yT row stride (bf16)
#define NROW 84      // yT rows (reads reach row 81)
#define AST  136     // wA row stride (bf16)

// MFMA phase: out[h][il] = relu(sc[h]*(sum) + tc[h]); A=wA (M=h), B=yin (N=il).
// PHASE==2: taps (il, il+1), store il<66, zero outside gl in [0,1022)
// PHASE==3: taps (il, il-1), store 1<=il<66, zero outside gl in [0,1023)
// PHASE==4: taps (il, il-1), store 2<=il<66 to global X (no BN, just bias)
template<int PHASE>
__device__ __forceinline__ void mfma_phase(
    const uint16_t* yin, uint16_t* yout, uint16_t* Xg, const uint16_t* wAs,
    const float* p_g, const float* p_be, const float* p_m, const float* p_v,
    const float* p_b, int lane, int wv, int l0)
{
  const int m0 = wv * 16;
  const int lm = lane & 15, lq = lane >> 4;
  float scr[4], tcr[4];
#pragma unroll
  for (int r = 0; r < 4; ++r) {
    int hr = m0 + lq * 4 + r;
    if constexpr (PHASE == 4) {
      scr[r] = 1.f; tcr[r] = p_b[hr];
    } else {
      float s = p_g[hr] * __builtin_amdgcn_rsqf(p_v[hr] + 1e-5f);
      scr[r] = s; tcr[r] = (p_b[hr] - p_m[hr]) * s + p_be[hr];
    }
  }
  bf16x8 af[4];
#pragma unroll
  for (int kc = 0; kc < 4; ++kc)
    af[kc] = *(const bf16x8*)&wAs[(m0 + lm) * AST + kc * 32 + lq * 8];
  const f32x4 Z = {0.f, 0.f, 0.f, 0.f};
#pragma unroll
  for (int nt = 0; nt < 5; ++nt) {
    f32x4 acc = Z;
#pragma unroll
    for (int kc = 0; kc < 4; ++kc) {
      int half = kc >> 1;
      int rT = nt * 16 + lm + 1 + (PHASE == 2 ? half : -half);
      bf16x8 bf_ = *(const bf16x8*)&yin[rT * YT + (kc & 1) * 32 + lq * 8];
      acc = MFMA16(af[kc], bf_, acc);
    }
    int il = nt * 16 + lm;
    int gl = l0 - 2 + il;
#pragma unroll
    for (int r = 0; r < 4; ++r) {
      int h = m0 + lq * 4 + r;
      float v = fmaxf(acc[r] * scr[r] + tcr[r], 0.f);
      if constexpr (PHASE == 2) {
        if (il < 66) yout[(il + 1) * YT + h] = (gl >= 0 && gl < 1022) ? f2bf(v) : (uint16_t)0;
      } else if constexpr (PHASE == 3) {
        if (il >= 1 && il < 66) yout[(il + 1) * YT + h] = (gl >= 0 && gl < 1023) ? f2bf(v) : (uint16_t)0;
      } else {
        if (il >= 2 && il < 66) Xg[(size_t)gl * 64 + h] = f2bf(v);
      }
    }
  }
}

__global__ __launch_bounds__(256, 3) void conv_stack_k(
    const float* __restrict__ inp,
    const float* __restrict__ w1p, const float* __restrict__ b1p,
    const float* __restrict__ g1p, const float* __restrict__ be1p,
    const float* __restrict__ m1p, const float* __restrict__ v1p,
    const float* __restrict__ w2p, const float* __restrict__ b2p,
    const float* __restrict__ g2p, const float* __restrict__ be2p,
    const float* __restrict__ m2p, const float* __restrict__ v2p,
    const float* __restrict__ t1p, const float* __restrict__ tb1p,
    const float* __restrict__ g3p, const float* __restrict__ be3p,
    const float* __restrict__ m3p, const float* __restrict__ v3p,
    const float* __restrict__ t2p, const float* __restrict__ tb2p,
    uint16_t* __restrict__ X)
{
  __shared__ __align__(16) uint16_t yTA[NROW * YT];
  __shared__ __align__(16) uint16_t yTB[NROW * YT];
  __shared__ __align__(16) uint16_t wAs[64 * AST];
  __shared__ float xs[6][YT];
  const int tid  = threadIdx.x;
  const int lane = tid & 63;
  const int wv   = tid >> 6;
  const int t    = blockIdx.y;
  const int l0   = blockIdx.x * 64;

  // zero yT buffers (rows outside the written window must read as 0)
  for (int i = tid; i < NROW * YT; i += 256) { yTA[i] = 0; yTB[i] = 0; }

  // stage input window xs[c][il], gl = l0-2+il
  for (int i = tid; i < 6 * YT; i += 256) {
    int c = i % 6, il = i / 6;
    int gl = l0 - 2 + il;
    float v = 0.f;
    if (gl >= 0 && gl < 1024) v = inp[(size_t)t * 6144 + (size_t)gl * 6 + c];
    xs[c][il] = v;
  }

  // stage phase-2 weights: w2p[h][c][k] -> wAs[h][k*64+c]
  for (int i = tid; i < 4096; i += 256) {
    int hh = i >> 6, cc = i & 63;
    float2 q = *(const float2*)(w2p + (size_t)i * 2);
    wAs[hh * AST + cc]      = f2bf(q.x);
    wAs[hh * AST + 64 + cc] = f2bf(q.y);
  }
  __syncthreads();

  // ---- phase 1 (VALU): y1 = relu(bn1(conv1(x))), il<67, write yTA[il+1][h]
  {
    const int h = lane;  // note: each wave covers all 64 h, splits columns
    float wr[12];
#pragma unroll
    for (int i = 0; i < 6; ++i) {
      float2 q = *(const float2*)(w1p + h * 12 + i * 2);
      wr[i * 2] = q.x; wr[i * 2 + 1] = q.y;
    }
    float sc = g1p[h] * __builtin_amdgcn_rsqf(v1p[h] + 1e-5f);
    float tc = (b1p[h] - m1p[h]) * sc + be1p[h];
#pragma unroll 1
    for (int base = wv * 4; base < 67; base += 16) {
      float a0 = 0, a1 = 0, a2 = 0, a3 = 0;
#pragma unroll
      for (int c = 0; c < 6; ++c) {
        float4 v = *(const float4*)&xs[c][base];
        float s4 = xs[c][base + 4];
        float k0 = wr[c * 2], k1 = wr[c * 2 + 1];
        a0 += v.x * k0 + v.y * k1;
        a1 += v.y * k0 + v.z * k1;
        a2 += v.z * k0 + v.w * k1;
        a3 += v.w * k0 + s4 * k1;
      }
      float r[4] = {a0, a1, a2, a3};
#pragma unroll
      for (int j = 0; j < 4; ++j) {
        int il = base + j;
        if (il < 67) {
          int gl = l0 - 2 + il;
          yTA[(il + 1) * YT + h] =
              (gl >= 0 && gl < 1023) ? f2bf(fmaxf(r[j] * sc + tc, 0.f)) : (uint16_t)0;
        }
      }
    }
  }
  __syncthreads();

  // ---- phase 2 (MFMA): yTA -> yTB
  mfma_phase<2>(yTA, yTB, nullptr, wAs, g2p, be2p, m2p, v2p, b2p, lane, wv, l0);
  __syncthreads();

  // stage phase-3 weights: t1p[c][h][k] -> wAs[h][k*64+c]
  for (int i = tid; i < 4096; i += 256) {
    int cc = i >> 6, hh = i & 63;
    float2 q = *(const float2*)(t1p + (size_t)i * 2);
    wAs[hh * AST + cc]      = f2bf(q.x);
    wAs[hh * AST + 64 + cc] = f2bf(q.y);
  }
  __syncthreads();

  // ---- phase 3 (MFMA): yTB -> yTA
  mfma_phase<3>(yTB, yTA, nullptr, wAs, g3p, be3p, m3p, v3p, tb1p, lane, wv, l0);
  __syncthreads();

  // stage phase-4 weights: t2p[c][h][k] -> wAs[h][k*64+c]
  for (int i = tid; i < 4096; i += 256) {
    int cc = i >> 6, hh = i & 63;
    float2 q = *(const float2*)(t2p + (size_t)i * 2);
    wAs[hh * AST + cc]      = f2bf(q.x);
    wAs[hh * AST + 64 + cc] = f2bf(q.y);
  }
  __syncthreads();

  // ---- phase 4 (MFMA): yTA -> global X slot t+1 (relu(conv+b), no BN)
  mfma_phase<4>(yTA, nullptr, X + (size_t)(t + 1) * 65536, wAs,
                nullptr, nullptr, nullptr, nullptr, tb2p, lane, wv, l0);
}

// ============================== LSTM =======================================
// 64 blocks x 16 batch rows; 4 waves; wave w owns gate cols {16w,+64,+128,+192}
// so each lane holds i,f,g,o of its cells. K=128 = [x_t | h] via 4 MFMA chunks.
// h exchanged through double-buffered LDS (row stride 72 -> 2-way aliasing,
// free). One __syncthreads per step.
#define HSTR 72

#define LSTM_STEP(T_, XC, XN, BR, BW) do {                                     \
    if ((T_) + 1 < 512) {                                                      \
      const uint16_t* xp_ = Xb + (size_t)((T_) + 2) * 65536                    \
                          + (size_t)(l0 + (lane & 15)) * 64 + kgrp;            \
      XN[0] = *(const bf16x8*)xp_;                                             \
      XN[1] = *(const bf16x8*)(xp_ + 32);                                      \
    }                                                                          \
    bf16x8 hf0_ = *(const bf16x8*)&hl[BR][(lane & 15) * HSTR + kgrp];          \
    bf16x8 hf1_ = *(const bf16x8*)&hl[BR][(lane & 15) * HSTR + 32 + kgrp];     \
    f32x4 ai_ = Z4, af_ = Z4, ag_ = Z4, ao_ = Z4;                              \
    ai_ = MFMA16(XC[0], bfr[0][0], ai_); af_ = MFMA16(XC[0], bfr[1][0], af_);  \
    ag_ = MFMA16(XC[0], bfr[2][0], ag_); ao_ = MFMA16(XC[0], bfr[3][0], ao_);  \
    ai_ = MFMA16(XC[1], bfr[0][1], ai_); af_ = MFMA16(XC[1], bfr[1][1], af_);  \
    ag_ = MFMA16(XC[1], bfr[2][1], ag_); ao_ = MFMA16(XC[1], bfr[3][1], ao_);  \
    ai_ = MFMA16(hf0_,  bfr[0][2], ai_); af_ = MFMA16(hf0_,  bfr[1][2], af_);  \
    ag_ = MFMA16(hf0_,  bfr[2][2], ag_); ao_ = MFMA16(hf0_,  bfr[3][2], ao_);  \
    ai_ = MFMA16(hf1_,  bfr[0][3], ai_); af_ = MFMA16(hf1_,  bfr[1][3], af_);  \
    ag_ = MFMA16(hf1_,  bfr[2][3], ag_); ao_ = MFMA16(hf1_,  bfr[3][3], ao_);  \
    _Pragma("unroll")                                                          \
    for (int r_ = 0; r_ < 4; ++r_) {                                           \
      float ii = fsig(ai_[r_] + bi0);                                          \
      float ff = fsig(af_[r_] + bi1);                                          \
      float gg = ftanh(ag_[r_] + bi2);                                         \
      float oo = fsig(ao_[r_] + bi3);                                          \
      creg[r_] = ff * creg[r_] + ii * gg;                                      \
      hprev[r_] = oo * ftanh(creg[r_]);                                        \
      uint16_t hb_ = f2bf(hprev[r_]);                                          \
      hl[BW][(r0 + r_) * HSTR + hcol] = hb_;                                   \
      Xb[(size_t)(T_) * 65536 + (size_t)(l0 + r0 + r_) * 64 + hcol] = hb_;     \
    }                                                                          \
    __syncthreads();                                                           \
  } while (0)

__global__ __launch_bounds__(256) void lstm_k(
    const float* __restrict__ h0p, const float* __restrict__ c0p,
    const float* __restrict__ wihp, const float* __restrict__ whhp,
    const float* __restrict__ bihp, const float* __restrict__ bhhp,
    uint16_t* __restrict__ Xb, float* __restrict__ outp)
{
  __shared__ __align__(16) uint16_t hl[2][16 * HSTR];
  const int tid  = threadIdx.x;
  const int lane = tid & 63;
  const int wv   = tid >> 6;
  const int l0   = blockIdx.x << 4;
  const int hcol = (wv << 4) | (lane & 15);
  const int r0   = (lane >> 4) << 2;
  const int kgrp = (lane >> 4) << 3;

  bf16x8 bfr[4][4];
#pragma unroll
  for (int nt = 0; nt < 4; ++nt) {
    int n = nt * 64 + hcol;
#pragma unroll
    for (int kc = 0; kc < 4; ++kc) {
      int k0 = kc * 32 + kgrp;
      const float* src = (k0 < 64) ? (wihp + (size_t)n * 64 + k0)
                                   : (whhp + (size_t)n * 64 + (k0 - 64));
      bf16x8 f;
#pragma unroll
      for (int j = 0; j < 8; ++j) f[j] = (short)f2bf(src[j]);
      bfr[nt][kc] = f;
    }
  }
  float bi0 = bihp[hcol]       + bhhp[hcol];
  float bi1 = bihp[64 + hcol]  + bhhp[64 + hcol];
  float bi2 = bihp[128 + hcol] + bhhp[128 + hcol];
  float bi3 = bihp[192 + hcol] + bhhp[192 + hcol];

  float creg[4], hprev[4] = {0.f, 0.f, 0.f, 0.f};
#pragma unroll
  for (int r = 0; r < 4; ++r)
    creg[r] = c0p[(size_t)(l0 + r0 + r) * 64 + hcol];

  {
    int row = tid >> 4, col = (tid & 15) << 2;
    const float* sp = h0p + (size_t)(l0 + row) * 64 + col;
    int b = row * HSTR + col;
    hl[0][b]     = f2bf(sp[0]); hl[0][b + 1] = f2bf(sp[1]);
    hl[0][b + 2] = f2bf(sp[2]); hl[0][b + 3] = f2bf(sp[3]);
  }

  bf16x8 xA[2], xB[2];
  {
    const uint16_t* xp = Xb + 65536 + (size_t)(l0 + (lane & 15)) * 64 + kgrp;
    xA[0] = *(const bf16x8*)xp;
    xA[1] = *(const bf16x8*)(xp + 32);
  }
  __syncthreads();

  const f32x4 Z4 = {0.f, 0.f, 0.f, 0.f};
#pragma unroll 1
  for (int t2 = 0; t2 < 512; t2 += 2) {
    LSTM_STEP(t2,     xA, xB, 0, 1);
    LSTM_STEP(t2 + 1, xB, xA, 1, 0);
  }

#pragma unroll
  for (int r = 0; r < 4; ++r) {
    int gr = l0 + r0 + r;
    outp[524288 + (size_t)gr * 64 + hcol] = hprev[r];
    outp[589824 + (size_t)gr * 64 + hcol] = creg[r];
  }
}

// ========================= output projection ===============================
__global__ __launch_bounds__(256) void proj_k(
    const uint16_t* __restrict__ Hb, const float* __restrict__ owp,
    const float* __restrict__ obp, float* __restrict__ outp)
{
  __shared__ float ows[64];
  if (threadIdx.x < 64) ows[threadIdx.x] = owp[threadIdx.x];
  __syncthreads();
  int idx = blockIdx.x * 256 + threadIdx.x;
  const uint16_t* hp = Hb + (size_t)idx * 64;
  float s = obp[0];
#pragma unroll
  for (int j = 0; j < 8; ++j) {
    bf16x8 hv = *(const bf16x8*)(hp + j * 8);
#pragma unroll
    for (int e = 0; e < 8; ++e) s += bf2f((uint16_t)hv[e]) * ows[j * 8 + e];
  }
  outp[idx] = s;
}

// ============================== launch =====================================
extern "C" void kernel_launch(void* const* d_in, const int* in_sizes, int n_in,
                              void* d_out, int out_size, void* d_ws, size_t ws_size,
                              hipStream_t stream)
{
  (void)in_sizes; (void)n_in; (void)out_size;
  if (ws_size < (size_t)513 * 65536 * 2) return;   // ws guard

  const float* inp = (const float*)d_in[0];
  const float* h0p = (const float*)d_in[1];
  const float* c0p = (const float*)d_in[2];
  const float* w1  = (const float*)d_in[3];
  const float* b1  = (const float*)d_in[4];
  const float* g1  = (const float*)d_in[5];
  const float* be1 = (const float*)d_in[6];
  const float* m1  = (const float*)d_in[7];
  const float* v1  = (const float*)d_in[8];
  const float* w2  = (const float*)d_in[9];
  const float* b2  = (const float*)d_in[10];
  const float* g2  = (const float*)d_in[11];
  const float* be2 = (const float*)d_in[12];
  const float* m2  = (const float*)d_in[13];
  const float* v2  = (const float*)d_in[14];
  const float* tw1 = (const float*)d_in[15];
  const float* tb1 = (const float*)d_in[16];
  const float* g3  = (const float*)d_in[17];
  const float* be3 = (const float*)d_in[18];
  const float* m3  = (const float*)d_in[19];
  const float* v3  = (const float*)d_in[20];
  const float* tw2 = (const float*)d_in[21];
  const float* tb2 = (const float*)d_in[22];
  const float* wih = (const float*)d_in[23];
  const float* whh = (const float*)d_in[24];
  const float* bih = (const float*)d_in[25];
  const float* bhh = (const float*)d_in[26];
  const float* ow  = (const float*)d_in[27];
  const float* ob  = (const float*)d_in[28];

  uint16_t* Xb   = (uint16_t*)d_ws;
  float*    outp = (float*)d_out;

  conv_stack_k<<<dim3(16, 512), 256, 0, stream>>>(
      inp, w1, b1, g1, be1, m1, v1, w2, b2, g2, be2, m2, v2,
      tw1, tb1, g3, be3, m3, v3, tw2, tb2, Xb);
  lstm_k<<<64, 256, 0, stream>>>(h0p, c0p, wih, whh, bih, bhh, Xb, outp);
  proj_k<<<2048, 256, 0, stream>>>(Xb, ow, ob, outp);
}

// Round 7
// 452.085 us; speedup vs baseline: 39.5070x; 1.0583x over previous
//
#include <hip/hip_runtime.h>
#include <hip/hip_bf16.h>
#include <stdint.h>

// ---------------------------------------------------------------------------
// CNNLSTM: conv1(6->64,k2) BN ReLU -> conv2(64->64,k2) BN ReLU ->
//          convT1(64->64,k2) BN ReLU -> convT2(64->64,k2) ReLU ->
//          LSTM(T=512, batch=1024, H=64) -> linear(64->1)
// Device I/O: FP32. Conv phases 2-4 on MFMA (bf16 in, fp32 accum); phase 1
// (K=6) VALU. LSTM: MFMA bf16, fp32 cell; raw s_barrier (lgkmcnt-only) so the
// per-step global h-store and x-prefetch stay in flight (no vmcnt drain —
// round-6 __syncthreads drained stores every step: ~80% stall);
// x-part gates (Wih) computed one step ahead, off the h-dependent chain.
// ws layout: 513 slots of 1024*64 bf16 (slot s = ws + s*65536 elems).
//   conv writes x_t to slot t+1 ; LSTM reads slot t+1, writes h_t to slot t ;
//   projection reads h_t at slot t.  ws bytes: 513*65536*2 = 67,239,936.
// ---------------------------------------------------------------------------

typedef __attribute__((ext_vector_type(8))) short bf16x8;
typedef __attribute__((ext_vector_type(4))) float f32x4;

__device__ __forceinline__ float bf2f(uint16_t u) {
  union { uint32_t i; float f; } v; v.i = ((uint32_t)u) << 16; return v.f;
}
__device__ __forceinline__ uint16_t f2bf(float f) {
  union { float f; uint32_t i; } v; v.f = f;
  return (uint16_t)((v.i + 0x7FFFu + ((v.i >> 16) & 1u)) >> 16);  // RNE
}
__device__ __forceinline__ float fexp(float x) { return __builtin_amdgcn_exp2f(x * 1.44269504088896340736f); }
__device__ __forceinline__ float frcp(float x) { return __builtin_amdgcn_rcpf(x); }
__device__ __forceinline__ float fsig(float x)  { return frcp(1.f + fexp(-x)); }
__device__ __forceinline__ float ftanh(float x) { return 1.f - 2.f * frcp(1.f + fexp(2.f * x)); }

#define MFMA16(a, b, c) __builtin_amdgcn_mfma_f32_16x16x32_bf16(a, b, c, 0, 0, 0)

// ============================ conv stack ===================================
// Grid: (16 chunks of 64 cols, 512 t). Block 256 thr = 4 waves.
// il -> global l: gl = l0 - 2 + il. yT row = il + 1.
#define YT   72      // yT row stride (bf16)
#define NROW 84      // yT rows (reads reach row 81)
#define AST  136     // wA row stride (bf16)

template<int PHASE>
__device__ __forceinline__ void mfma_phase(
    const uint16_t* yin, uint16_t* yout, uint16_t* Xg, const uint16_t* wAs,
    const float* p_g, const float* p_be, const float* p_m, const float* p_v,
    const float* p_b, int lane, int wv, int l0)
{
  const int m0 = wv * 16;
  const int lm = lane & 15, lq = lane >> 4;
  float scr[4], tcr[4];
#pragma unroll
  for (int r = 0; r < 4; ++r) {
    int hr = m0 + lq * 4 + r;
    if constexpr (PHASE == 4) {
      scr[r] = 1.f; tcr[r] = p_b[hr];
    } else {
      float s = p_g[hr] * __builtin_amdgcn_rsqf(p_v[hr] + 1e-5f);
      scr[r] = s; tcr[r] = (p_b[hr] - p_m[hr]) * s + p_be[hr];
    }
  }
  bf16x8 af[4];
#pragma unroll
  for (int kc = 0; kc < 4; ++kc)
    af[kc] = *(const bf16x8*)&wAs[(m0 + lm) * AST + kc * 32 + lq * 8];
  const f32x4 Z = {0.f, 0.f, 0.f, 0.f};
#pragma unroll
  for (int nt = 0; nt < 5; ++nt) {
    f32x4 acc = Z;
#pragma unroll
    for (int kc = 0; kc < 4; ++kc) {
      int half = kc >> 1;
      int rT = nt * 16 + lm + 1 + (PHASE == 2 ? half : -half);
      bf16x8 bf_ = *(const bf16x8*)&yin[rT * YT + (kc & 1) * 32 + lq * 8];
      acc = MFMA16(af[kc], bf_, acc);
    }
    int il = nt * 16 + lm;
    int gl = l0 - 2 + il;
#pragma unroll
    for (int r = 0; r < 4; ++r) {
      int h = m0 + lq * 4 + r;
      float v = fmaxf(acc[r] * scr[r] + tcr[r], 0.f);
      if constexpr (PHASE == 2) {
        if (il < 66) yout[(il + 1) * YT + h] = (gl >= 0 && gl < 1022) ? f2bf(v) : (uint16_t)0;
      } else if constexpr (PHASE == 3) {
        if (il >= 1 && il < 66) yout[(il + 1) * YT + h] = (gl >= 0 && gl < 1023) ? f2bf(v) : (uint16_t)0;
      } else {
        if (il >= 2 && il < 66) Xg[(size_t)gl * 64 + h] = f2bf(v);
      }
    }
  }
}

__global__ __launch_bounds__(256, 3) void conv_stack_k(
    const float* __restrict__ inp,
    const float* __restrict__ w1p, const float* __restrict__ b1p,
    const float* __restrict__ g1p, const float* __restrict__ be1p,
    const float* __restrict__ m1p, const float* __restrict__ v1p,
    const float* __restrict__ w2p, const float* __restrict__ b2p,
    const float* __restrict__ g2p, const float* __restrict__ be2p,
    const float* __restrict__ m2p, const float* __restrict__ v2p,
    const float* __restrict__ t1p, const float* __restrict__ tb1p,
    const float* __restrict__ g3p, const float* __restrict__ be3p,
    const float* __restrict__ m3p, const float* __restrict__ v3p,
    const float* __restrict__ t2p, const float* __restrict__ tb2p,
    uint16_t* __restrict__ X)
{
  __shared__ __align__(16) uint16_t yTA[NROW * YT];
  __shared__ __align__(16) uint16_t yTB[NROW * YT];
  __shared__ __align__(16) uint16_t wAs[64 * AST];
  __shared__ float xs[6][YT];
  const int tid  = threadIdx.x;
  const int lane = tid & 63;
  const int wv   = tid >> 6;
  const int t    = blockIdx.y;
  const int l0   = blockIdx.x * 64;

  for (int i = tid; i < NROW * YT; i += 256) { yTA[i] = 0; yTB[i] = 0; }

  for (int i = tid; i < 6 * YT; i += 256) {
    int c = i % 6, il = i / 6;
    int gl = l0 - 2 + il;
    float v = 0.f;
    if (gl >= 0 && gl < 1024) v = inp[(size_t)t * 6144 + (size_t)gl * 6 + c];
    xs[c][il] = v;
  }

  for (int i = tid; i < 4096; i += 256) {
    int hh = i >> 6, cc = i & 63;
    float2 q = *(const float2*)(w2p + (size_t)i * 2);
    wAs[hh * AST + cc]      = f2bf(q.x);
    wAs[hh * AST + 64 + cc] = f2bf(q.y);
  }
  __syncthreads();

  // ---- phase 1 (VALU): y1 = relu(bn1(conv1(x))), il<67, write yTA[il+1][h]
  {
    const int h = lane;
    float wr[12];
#pragma unroll
    for (int i = 0; i < 6; ++i) {
      float2 q = *(const float2*)(w1p + h * 12 + i * 2);
      wr[i * 2] = q.x; wr[i * 2 + 1] = q.y;
    }
    float sc = g1p[h] * __builtin_amdgcn_rsqf(v1p[h] + 1e-5f);
    float tc = (b1p[h] - m1p[h]) * sc + be1p[h];
#pragma unroll 1
    for (int base = wv * 4; base < 67; base += 16) {
      float a0 = 0, a1 = 0, a2 = 0, a3 = 0;
#pragma unroll
      for (int c = 0; c < 6; ++c) {
        float4 v = *(const float4*)&xs[c][base];
        float s4 = xs[c][base + 4];
        float k0 = wr[c * 2], k1 = wr[c * 2 + 1];
        a0 += v.x * k0 + v.y * k1;
        a1 += v.y * k0 + v.z * k1;
        a2 += v.z * k0 + v.w * k1;
        a3 += v.w * k0 + s4 * k1;
      }
      float r[4] = {a0, a1, a2, a3};
#pragma unroll
      for (int j = 0; j < 4; ++j) {
        int il = base + j;
        if (il < 67) {
          int gl = l0 - 2 + il;
          yTA[(il + 1) * YT + h] =
              (gl >= 0 && gl < 1023) ? f2bf(fmaxf(r[j] * sc + tc, 0.f)) : (uint16_t)0;
        }
      }
    }
  }
  __syncthreads();

  mfma_phase<2>(yTA, yTB, nullptr, wAs, g2p, be2p, m2p, v2p, b2p, lane, wv, l0);
  __syncthreads();

  for (int i = tid; i < 4096; i += 256) {
    int cc = i >> 6, hh = i & 63;
    float2 q = *(const float2*)(t1p + (size_t)i * 2);
    wAs[hh * AST + cc]      = f2bf(q.x);
    wAs[hh * AST + 64 + cc] = f2bf(q.y);
  }
  __syncthreads();

  mfma_phase<3>(yTB, yTA, nullptr, wAs, g3p, be3p, m3p, v3p, tb1p, lane, wv, l0);
  __syncthreads();

  for (int i = tid; i < 4096; i += 256) {
    int cc = i >> 6, hh = i & 63;
    float2 q = *(const float2*)(t2p + (size_t)i * 2);
    wAs[hh * AST + cc]      = f2bf(q.x);
    wAs[hh * AST + 64 + cc] = f2bf(q.y);
  }
  __syncthreads();

  mfma_phase<4>(yTA, nullptr, X + (size_t)(t + 1) * 65536, wAs,
                nullptr, nullptr, nullptr, nullptr, tb2p, lane, wv, l0);
}

// ============================== LSTM =======================================
// 64 blocks x 16 batch rows; 4 waves; wave w owns gate cols {16w,+64,+128,+192}
// so each lane holds i,f,g,o of its cells. K=128 = [x_t | h].
// Pipeline per step t:
//   h-MFMAs (2 dep per gate, on top of precomputed x-part AXC) -> pointwise ->
//   ds_write h + global store h (floats) -> prefetch x_{t+2} ->
//   x-part MFMAs for t+1 (AXN, reg-only) -> lgkmcnt(0) + raw s_barrier.
// No vmcnt drain at the barrier: global h-stores/x-loads stay in flight.
#define HSTR 72

#define LSTM_STEP(T_, AXC, AXN, XNXT, XLD, BR, BW) do {                        \
    bf16x8 hf0_ = *(const bf16x8*)&hl[BR][(lane & 15) * HSTR + kgrp];          \
    bf16x8 hf1_ = *(const bf16x8*)&hl[BR][(lane & 15) * HSTR + 32 + kgrp];     \
    f32x4 ai_ = AXC[0], af_ = AXC[1], ag_ = AXC[2], ao_ = AXC[3];              \
    ai_ = MFMA16(hf0_, bfr[0][2], ai_); af_ = MFMA16(hf0_, bfr[1][2], af_);    \
    ag_ = MFMA16(hf0_, bfr[2][2], ag_); ao_ = MFMA16(hf0_, bfr[3][2], ao_);    \
    ai_ = MFMA16(hf1_, bfr[0][3], ai_); af_ = MFMA16(hf1_, bfr[1][3], af_);    \
    ag_ = MFMA16(hf1_, bfr[2][3], ag_); ao_ = MFMA16(hf1_, bfr[3][3], ao_);    \
    _Pragma("unroll")                                                          \
    for (int r_ = 0; r_ < 4; ++r_) {                                           \
      float ii = fsig(ai_[r_] + bi0);                                          \
      float ff = fsig(af_[r_] + bi1);                                          \
      float gg = ftanh(ag_[r_] + bi2);                                         \
      float oo = fsig(ao_[r_] + bi3);                                          \
      creg[r_] = ff * creg[r_] + ii * gg;                                      \
      hprev[r_] = oo * ftanh(creg[r_]);                                        \
      uint16_t hb_ = f2bf(hprev[r_]);                                          \
      hl[BW][(r0 + r_) * HSTR + hcol] = hb_;                                   \
      Xb[(size_t)(T_) * 65536 + (size_t)(l0 + r0 + r_) * 64 + hcol] = hb_;     \
    }                                                                          \
    if ((T_) + 2 < 512) {                                                      \
      const uint16_t* xp_ = Xb + (size_t)((T_) + 3) * 65536                    \
                          + (size_t)(l0 + (lane & 15)) * 64 + kgrp;            \
      XLD[0] = *(const bf16x8*)xp_;                                            \
      XLD[1] = *(const bf16x8*)(xp_ + 32);                                     \
    }                                                                          \
    if ((T_) + 1 < 512) {                                                      \
      AXN[0] = MFMA16(XNXT[1], bfr[0][1], MFMA16(XNXT[0], bfr[0][0], Z4));     \
      AXN[1] = MFMA16(XNXT[1], bfr[1][1], MFMA16(XNXT[0], bfr[1][0], Z4));     \
      AXN[2] = MFMA16(XNXT[1], bfr[2][1], MFMA16(XNXT[0], bfr[2][0], Z4));     \
      AXN[3] = MFMA16(XNXT[1], bfr[3][1], MFMA16(XNXT[0], bfr[3][0], Z4));     \
    }                                                                          \
    asm volatile("s_waitcnt lgkmcnt(0)" ::: "memory");                         \
    __builtin_amdgcn_s_barrier();                                              \
    asm volatile("" ::: "memory");                                             \
  } while (0)

__global__ __launch_bounds__(256) void lstm_k(
    const float* __restrict__ h0p, const float* __restrict__ c0p,
    const float* __restrict__ wihp, const float* __restrict__ whhp,
    const float* __restrict__ bihp, const float* __restrict__ bhhp,
    uint16_t* __restrict__ Xb, float* __restrict__ outp)
{
  __shared__ __align__(16) uint16_t hl[2][16 * HSTR];
  const int tid  = threadIdx.x;
  const int lane = tid & 63;
  const int wv   = tid >> 6;
  const int l0   = blockIdx.x << 4;
  const int hcol = (wv << 4) | (lane & 15);
  const int r0   = (lane >> 4) << 2;
  const int kgrp = (lane >> 4) << 3;
  const f32x4 Z4 = {0.f, 0.f, 0.f, 0.f};

  bf16x8 bfr[4][4];
#pragma unroll
  for (int nt = 0; nt < 4; ++nt) {
    int n = nt * 64 + hcol;
#pragma unroll
    for (int kc = 0; kc < 4; ++kc) {
      int k0 = kc * 32 + kgrp;
      const float* src = (k0 < 64) ? (wihp + (size_t)n * 64 + k0)
                                   : (whhp + (size_t)n * 64 + (k0 - 64));
      bf16x8 f;
#pragma unroll
      for (int j = 0; j < 8; ++j) f[j] = (short)f2bf(src[j]);
      bfr[nt][kc] = f;
    }
  }
  float bi0 = bihp[hcol]       + bhhp[hcol];
  float bi1 = bihp[64 + hcol]  + bhhp[64 + hcol];
  float bi2 = bihp[128 + hcol] + bhhp[128 + hcol];
  float bi3 = bihp[192 + hcol] + bhhp[192 + hcol];

  float creg[4], hprev[4] = {0.f, 0.f, 0.f, 0.f};
#pragma unroll
  for (int r = 0; r < 4; ++r)
    creg[r] = c0p[(size_t)(l0 + r0 + r) * 64 + hcol];

  {
    int row = tid >> 4, col = (tid & 15) << 2;
    const float* sp = h0p + (size_t)(l0 + row) * 64 + col;
    int b = row * HSTR + col;
    hl[0][b]     = f2bf(sp[0]); hl[0][b + 1] = f2bf(sp[1]);
    hl[0][b + 2] = f2bf(sp[2]); hl[0][b + 3] = f2bf(sp[3]);
  }

  // preload x_0 (slot 1), x_1 (slot 2); precompute x-part gates for t=0
  bf16x8 xA[2], xB[2];
  {
    const uint16_t* xp = Xb + 65536 + (size_t)(l0 + (lane & 15)) * 64 + kgrp;
    xA[0] = *(const bf16x8*)xp;
    xA[1] = *(const bf16x8*)(xp + 32);
    const uint16_t* xq = xp + 65536;
    xB[0] = *(const bf16x8*)xq;
    xB[1] = *(const bf16x8*)(xq + 32);
  }
  f32x4 axA[4], axB[4];
#pragma unroll
  for (int g = 0; g < 4; ++g)
    axA[g] = MFMA16(xA[1], bfr[g][1], MFMA16(xA[0], bfr[g][0], Z4));
  __syncthreads();

#pragma unroll 1
  for (int t2 = 0; t2 < 512; t2 += 2) {
    LSTM_STEP(t2,     axA, axB, xB, xA, 0, 1);
    LSTM_STEP(t2 + 1, axB, axA, xA, xB, 1, 0);
  }

  // hT at out+524288, cT at out+589824 (fp32)
#pragma unroll
  for (int r = 0; r < 4; ++r) {
    int gr = l0 + r0 + r;
    outp[524288 + (size_t)gr * 64 + hcol] = hprev[r];
    outp[589824 + (size_t)gr * 64 + hcol] = creg[r];
  }
}

// ========================= output projection ===============================
__global__ __launch_bounds__(256) void proj_k(
    const uint16_t* __restrict__ Hb, const float* __restrict__ owp,
    const float* __restrict__ obp, float* __restrict__ outp)
{
  __shared__ float ows[64];
  if (threadIdx.x < 64) ows[threadIdx.x] = owp[threadIdx.x];
  __syncthreads();
  int idx = blockIdx.x * 256 + threadIdx.x;
  const uint16_t* hp = Hb + (size_t)idx * 64;
  float s = obp[0];
#pragma unroll
  for (int j = 0; j < 8; ++j) {
    bf16x8 hv = *(const bf16x8*)(hp + j * 8);
#pragma unroll
    for (int e = 0; e < 8; ++e) s += bf2f((uint16_t)hv[e]) * ows[j * 8 + e];
  }
  outp[idx] = s;
}

// ============================== launch =====================================
extern "C" void kernel_launch(void* const* d_in, const int* in_sizes, int n_in,
                              void* d_out, int out_size, void* d_ws, size_t ws_size,
                              hipStream_t stream)
{
  (void)in_sizes; (void)n_in; (void)out_size;
  if (ws_size < (size_t)513 * 65536 * 2) return;   // ws guard

  const float* inp = (const float*)d_in[0];
  const float* h0p = (const float*)d_in[1];
  const float* c0p = (const float*)d_in[2];
  const float* w1  = (const float*)d_in[3];
  const float* b1  = (const float*)d_in[4];
  const float* g1  = (const float*)d_in[5];
  const float* be1 = (const float*)d_in[6];
  const float* m1  = (const float*)d_in[7];
  const float* v1  = (const float*)d_in[8];
  const float* w2  = (const float*)d_in[9];
  const float* b2  = (const float*)d_in[10];
  const float* g2  = (const float*)d_in[11];
  const float* be2 = (const float*)d_in[12];
  const float* m2  = (const float*)d_in[13];
  const float* v2  = (const float*)d_in[14];
  const float* tw1 = (const float*)d_in[15];
  const float* tb1 = (const float*)d_in[16];
  const float* g3  = (const float*)d_in[17];
  const float* be3 = (const float*)d_in[18];
  const float* m3  = (const float*)d_in[19];
  const float* v3  = (const float*)d_in[20];
  const float* tw2 = (const float*)d_in[21];
  const float* tb2 = (const float*)d_in[22];
  const float* wih = (const float*)d_in[23];
  const float* whh = (const float*)d_in[24];
  const float* bih = (const float*)d_in[25];
  const float* bhh = (const float*)d_in[26];
  const float* ow  = (const float*)d_in[27];
  const float* ob  = (const float*)d_in[28];

  uint16_t* Xb   = (uint16_t*)d_ws;
  float*    outp = (float*)d_out;

  conv_stack_k<<<dim3(16, 512), 256, 0, stream>>>(
      inp, w1, b1, g1, be1, m1, v1, w2, b2, g2, be2, m2, v2,
      tw1, tb1, g3, be3, m3, v3, tw2, tb2, Xb);
  lstm_k<<<64, 256, 0, stream>>>(h0p, c0p, wih, whh, bih, bhh, Xb, outp);
  proj_k<<<2048, 256, 0, stream>>>(Xb, ow, ob, outp);
}